// Round 6
// baseline (2348.533 us; speedup 1.0000x reference)
//
#include <hip/hip_runtime.h>

typedef short bf16x8 __attribute__((ext_vector_type(8)));
typedef float f32x4  __attribute__((ext_vector_type(4)));
typedef unsigned short u16;

#define T_SEQ 2048
#define C_DIM 1024
#define NH 16
#define HS 64
#define S_SETS 1023
#define S_PAD 1024
#define SCALE 0.125f     // 1/sqrt(64)
#define NEG_BIG -1e30f

__device__ __forceinline__ float bf2f(u16 u) {
    unsigned int x = ((unsigned int)u) << 16;
    return __builtin_bit_cast(float, x);
}
__device__ __forceinline__ u16 f2bf(float f) {
    unsigned int x = __builtin_bit_cast(unsigned int, f);
    unsigned int r = (x + 0x7FFFu + ((x >> 16) & 1u)) >> 16;
    return (u16)r;
}
__device__ __forceinline__ f32x4 mfma16(bf16x8 a, bf16x8 b, f32x4 c) {
    return __builtin_amdgcn_mfma_f32_16x16x32_bf16(a, b, c, 0, 0, 0);
}

// -------- Kernel 0a: fp32 -> (hi, lo) bf16 split ----------------------------
__global__ __launch_bounds__(256) void conv_split(const float* __restrict__ in,
                                                  u16* __restrict__ hi,
                                                  u16* __restrict__ lo, int n4) {
    int i = blockIdx.x * 256 + threadIdx.x;
    if (i >= n4) return;
    float4 f = ((const float4*)in)[i];
    ushort4 h, l;
    h.x = f2bf(f.x); l.x = f2bf(f.x - bf2f(h.x));
    h.y = f2bf(f.y); l.y = f2bf(f.y - bf2f(h.y));
    h.z = f2bf(f.z); l.z = f2bf(f.z - bf2f(h.z));
    h.w = f2bf(f.w); l.w = f2bf(f.w - bf2f(h.w));
    ((ushort4*)hi)[i] = h;
    ((ushort4*)lo)[i] = l;
}

// -------- Kernel 0b: fp32 -> bf16 (plain) -----------------------------------
__global__ __launch_bounds__(256) void conv_plain(const float* __restrict__ in,
                                                  u16* __restrict__ out, int n4) {
    int i = blockIdx.x * 256 + threadIdx.x;
    if (i >= n4) return;
    float4 f = ((const float4*)in)[i];
    ushort4 o;
    o.x = f2bf(f.x); o.y = f2bf(f.y); o.z = f2bf(f.z); o.w = f2bf(f.w);
    ((ushort4*)out)[i] = o;
}

// -------- Kernel 1: qkv = x @ W_attn^T, split-bf16 (fp32-grade) -------------
// acc = xh*wh + xh*wl + xl*wh  (drops lo*lo, rel err ~1.6e-5). fp32 outputs.
__global__ __launch_bounds__(256) void gemm_qkv3(const u16* __restrict__ xh,
                                                 const u16* __restrict__ xl,
                                                 const u16* __restrict__ wh,
                                                 const u16* __restrict__ wl,
                                                 float* __restrict__ qf,
                                                 float* __restrict__ kf,
                                                 float* __restrict__ vf) {
    int wid  = blockIdx.x * 4 + (threadIdx.x >> 6);
    int lane = threadIdx.x & 63;
    int lm = lane & 15, quad = lane >> 4;
    int nt = wid % 192, mt = wid / 192;
    size_t aoff = (size_t)(mt * 16 + lm) * C_DIM + quad * 8;
    size_t boff = (size_t)(nt * 16 + lm) * C_DIM + quad * 8;
    const u16* xhr = xh + aoff; const u16* xlr = xl + aoff;
    const u16* whr = wh + boff; const u16* wlr = wl + boff;
    f32x4 acc = {0.f, 0.f, 0.f, 0.f};
    for (int k = 0; k < C_DIM; k += 32) {
        bf16x8 ah = *(const bf16x8*)(xhr + k);
        bf16x8 al = *(const bf16x8*)(xlr + k);
        bf16x8 bh = *(const bf16x8*)(whr + k);
        bf16x8 bl = *(const bf16x8*)(wlr + k);
        acc = mfma16(ah, bh, acc);
        acc = mfma16(ah, bl, acc);
        acc = mfma16(al, bh, acc);
    }
    int n = nt * 16 + lm;
    int which = n >> 10, h = (n >> 6) & 15, d = n & 63;
    for (int reg = 0; reg < 4; ++reg) {
        int m = mt * 16 + quad * 4 + reg;
        int b_ = m >> 11, t = m & 2047;
        size_t oi = (((size_t)(b_ * NH + h)) * T_SEQ + t) * HS + d;
        float val = acc[reg];
        if (which == 0)      qf[oi] = val;
        else if (which == 1) kf[oi] = val;
        else                 vf[oi] = val;
    }
}

// -------- Kernel 2: hierarchical set sums, fp32 in/out ----------------------
// Block per (b,h). Ksets/Vsets both s-major: [bh][s][d], s<1023 (row 1023 pad).
__global__ __launch_bounds__(256) void set_sums(const float* __restrict__ kf,
                                                const float* __restrict__ vf,
                                                float* __restrict__ Ksets,
                                                float* __restrict__ Vsets) {
    int bh  = blockIdx.x;
    int tid = threadIdx.x;
    __shared__ float lv0[512 * 16];
    __shared__ float lv1[256 * 16];
    for (int src = 0; src < 2; ++src) {
        const float* sp = src ? vf : kf;
        float* op = src ? Vsets : Ksets;
        for (int dc = 0; dc < 4; ++dc) {
            int dbase = dc * 16;
            for (int idx = tid; idx < 512 * 16; idx += 256) {
                int sg = idx >> 4, dd = idx & 15, d = dbase + dd;
                const float* p = sp + ((size_t)bh * T_SEQ + sg * 4) * HS + d;
                float s = p[0] + p[HS] + p[2 * HS] + p[3 * HS];
                lv0[sg * 16 + dd] = s;
                op[((size_t)bh * S_PAD + sg) * HS + d] = s;
            }
            __syncthreads();
            int nsets = 256, offset = 512, lvl = 1;
            while (nsets >= 1) {
                float* sbuf = (lvl & 1) ? lv0 : lv1;
                float* dbuf = (lvl & 1) ? lv1 : lv0;
                for (int idx = tid; idx < nsets * 16; idx += 256) {
                    int i = idx >> 4, dd = idx & 15, d = dbase + dd;
                    float s = sbuf[(2 * i) * 16 + dd] + sbuf[(2 * i + 1) * 16 + dd];
                    dbuf[i * 16 + dd] = s;
                    op[((size_t)bh * S_PAD + offset + i) * HS + d] = s;
                }
                __syncthreads();
                offset += nsets; nsets >>= 1; lvl++;
            }
        }
    }
}

// -------- Kernel 3: attention, pure VALU fp32 (diagnostic-correct) ----------
// Block per (bh, 16-query tile). thread = (row = tid>>4, g = tid&15).
__global__ __launch_bounds__(256) void attn_valu(const float* __restrict__ qf,
                                                 const float* __restrict__ kf,
                                                 const float* __restrict__ vf,
                                                 const float* __restrict__ Ksets,
                                                 const float* __restrict__ Vsets,
                                                 u16* __restrict__ attout) {
    int bh = blockIdx.y;
    int t0 = blockIdx.x * 16;
    int tid = threadIdx.x;
    int g = tid & 15, row = tid >> 4;
    __shared__ float qs[16][68];     // q tile (padded)
    __shared__ float Ks[128][68];    // K/V set chunk (padded)
    __shared__ float lg[16][1032];   // logits -> probabilities
    __shared__ float ptl[16];        // normalized tail prob

    // load q tile (16 x 64 fp32)
    {
        const float* qg = qf + ((size_t)bh * T_SEQ + t0) * HS;
        for (int i = tid; i < 1024; i += 256) qs[i >> 6][i & 63] = qg[i];
    }
    __syncthreads();

    // ---- logits: 8 chunks of 128 sets ----
    for (int chunk = 0; chunk < 8; ++chunk) {
        const float* kg = Ksets + ((size_t)bh * S_PAD + chunk * 128) * HS;
        for (int i = tid; i < 2048; i += 256) {  // 128 rows x 16 float4
            int sr = i >> 4, dv = i & 15;
            float4 f = *(const float4*)(kg + sr * 64 + dv * 4);
            Ks[sr][dv * 4 + 0] = f.x; Ks[sr][dv * 4 + 1] = f.y;
            Ks[sr][dv * 4 + 2] = f.z; Ks[sr][dv * 4 + 3] = f.w;
        }
        __syncthreads();
        for (int i = 0; i < 8; ++i) {
            int sl = g + i * 16;
            int s = chunk * 128 + sl;
            float acc = 0.f;
            #pragma unroll
            for (int dv = 0; dv < 16; ++dv) {
                float4 qv = *(const float4*)&qs[row][dv * 4];
                float4 kv = *(const float4*)&Ks[sl][dv * 4];
                acc += qv.x * kv.x + qv.y * kv.y + qv.z * kv.z + qv.w * kv.w;
            }
            float val = NEG_BIG;
            if (s < S_SETS) {
                int e = S_SETS - s;
                int l = __clz(e) - 22;              // level: L = 4<<l
                int i0 = s - (1024 - (1024 >> l));
                int r = (i0 + 1) * (4 << l) - 1;
                if (t0 + row >= r) val = acc * SCALE;
            }
            lg[row][s] = val;
        }
        __syncthreads();
    }

    // ---- softmax: wave wv handles rows wv*4..wv*4+3 ----
    int wv = tid >> 6, lane = tid & 63;
    for (int rr = 0; rr < 4; ++rr) {
        int r_ = wv * 4 + rr;
        int t = t0 + r_;
        float v[16], mx = NEG_BIG;
        for (int j = 0; j < 16; ++j) { v[j] = lg[r_][lane + j * 64]; mx = fmaxf(mx, v[j]); }
        for (int off = 32; off; off >>= 1) mx = fmaxf(mx, __shfl_xor(mx, off));
        // tail logit (lane = d)
        int len = (t & 3) + 1;
        const float* kp = kf + ((size_t)bh * T_SEQ + t) * HS + lane;
        float kt = 0.f;
        for (int j2 = 0; j2 < len; ++j2) kt += kp[-(j2 * HS)];
        float tl = qs[r_][lane] * kt;
        for (int off = 32; off; off >>= 1) tl += __shfl_xor(tl, off);
        tl *= SCALE;
        float Mx = fmaxf(mx, tl);
        float sm = 0.f;
        for (int j = 0; j < 16; ++j) { v[j] = __expf(v[j] - Mx); sm += v[j]; }
        for (int off = 32; off; off >>= 1) sm += __shfl_xor(sm, off);
        float pt = __expf(tl - Mx);
        float inv = 1.0f / (sm + pt);
        for (int j = 0; j < 16; ++j) lg[r_][lane + j * 64] = v[j] * inv;
        if (lane == 0) ptl[r_] = pt * inv;
    }
    __syncthreads();

    // ---- P @ Vsets: 8 chunks of 128 sets, thread owns (row, d=g+16j) ----
    float acc[4] = {0.f, 0.f, 0.f, 0.f};
    for (int chunk = 0; chunk < 8; ++chunk) {
        const float* vg = Vsets + ((size_t)bh * S_PAD + chunk * 128) * HS;
        for (int i = tid; i < 2048; i += 256) {
            int sr = i >> 4, dv = i & 15;
            float4 f = *(const float4*)(vg + sr * 64 + dv * 4);
            Ks[sr][dv * 4 + 0] = f.x; Ks[sr][dv * 4 + 1] = f.y;
            Ks[sr][dv * 4 + 2] = f.z; Ks[sr][dv * 4 + 3] = f.w;
        }
        __syncthreads();
        for (int sl = 0; sl < 128; ++sl) {
            float p = lg[row][chunk * 128 + sl];
            #pragma unroll
            for (int j = 0; j < 4; ++j) acc[j] += p * Ks[sl][g + 16 * j];
        }
        __syncthreads();
    }

    // ---- epilogue: + p_tail * V_tail, write bf16 ----
    int t = t0 + row;
    int b_ = bh >> 4, h_ = bh & 15;
    int len = (t & 3) + 1;
    for (int j = 0; j < 4; ++j) {
        int d = g + 16 * j;
        const float* vp = vf + ((size_t)bh * T_SEQ + t) * HS + d;
        float vt = 0.f;
        for (int j2 = 0; j2 < len; ++j2) vt += vp[-(j2 * HS)];
        float val = acc[j] + ptl[row] * vt;
        attout[((size_t)(b_ * T_SEQ + t)) * C_DIM + h_ * HS + d] = f2bf(val);
    }
}

// -------- Kernel 4: out = attout @ W_proj^T (bf16 MFMA, fp32 OUT) -----------
__global__ __launch_bounds__(256) void gemm_proj(const u16* __restrict__ a_,
                                                 const u16* __restrict__ w,
                                                 float* __restrict__ out) {
    int wid  = blockIdx.x * 4 + (threadIdx.x >> 6);
    int lane = threadIdx.x & 63;
    int lm = lane & 15, quad = lane >> 4;
    int nt = wid & 63, mt = wid >> 6;
    const u16* ar = a_ + (size_t)(mt * 16 + lm) * C_DIM + quad * 8;
    const u16* wr = w + (size_t)(nt * 16 + lm) * C_DIM + quad * 8;
    f32x4 acc = {0.f, 0.f, 0.f, 0.f};
    for (int k = 0; k < C_DIM; k += 32) {
        bf16x8 a = *(const bf16x8*)(ar + k);
        bf16x8 b = *(const bf16x8*)(wr + k);
        acc = mfma16(a, b, acc);
    }
    int n = nt * 16 + lm;
    for (int reg = 0; reg < 4; ++reg) {
        int m = mt * 16 + quad * 4 + reg;
        out[(size_t)m * C_DIM + n] = acc[reg];   // fp32 output — d_out is float*
    }
}

extern "C" void kernel_launch(void* const* d_in, const int* in_sizes, int n_in,
                              void* d_out, int out_size, void* d_ws, size_t ws_size,
                              hipStream_t stream) {
    const float* x     = (const float*)d_in[0];
    const float* Wattn = (const float*)d_in[1];
    const float* Wproj = (const float*)d_in[2];
    float* out = (float*)d_out;
    char* ws = (char*)d_ws;
    // workspace layout (~78 MB, with dead-buffer overlays)
    u16*   xh     = (u16*)(ws + 0);            //  8,388,608
    u16*   xl     = (u16*)(ws + 8388608);      //  8,388,608
    u16*   wh     = (u16*)(ws + 16777216);     //  6,291,456
    u16*   wl     = (u16*)(ws + 23068672);     //  6,291,456
    u16*   wp     = (u16*)(ws + 29360128);     //  2,097,152
    float* qf     = (float*)(ws + 31457280);   // 16,777,216
    float* kf     = (float*)(ws + 48234496);   // 16,777,216
    float* vf     = (float*)(ws + 65011712);   // 16,777,216  (end 81,788,928)
    // overlays (xh/xl/wh/wl dead after gemm_qkv3)
    float* Ksets  = (float*)(ws + 0);          //  8,388,608 (32*1024*64*4)
    float* Vsets  = (float*)(ws + 8388608);    //  8,388,608
    u16*   attout = (u16*)(ws + 16777216);     //  8,388,608 (over wh/wl, not wp)

    hipLaunchKernelGGL(conv_split, dim3(4096), dim3(256), 0, stream, x, xh, xl, 1048576);
    hipLaunchKernelGGL(conv_split, dim3(3072), dim3(256), 0, stream, Wattn, wh, wl, 786432);
    hipLaunchKernelGGL(conv_plain, dim3(1024), dim3(256), 0, stream, Wproj, wp, 262144);
    hipLaunchKernelGGL(gemm_qkv3, dim3(12288), dim3(256), 0, stream, xh, xl, wh, wl, qf, kf, vf);
    hipLaunchKernelGGL(set_sums, dim3(32), dim3(256), 0, stream, kf, vf, Ksets, Vsets);
    hipLaunchKernelGGL(attn_valu, dim3(128, 32), dim3(256), 0, stream, qf, kf, vf, Ksets, Vsets, attout);
    hipLaunchKernelGGL(gemm_proj, dim3(4096), dim3(256), 0, stream, attout, wp, out);
}

// Round 7
// 1152.146 us; speedup vs baseline: 2.0384x; 2.0384x over previous
//
#include <hip/hip_runtime.h>

typedef short bf16x8 __attribute__((ext_vector_type(8)));
typedef float f32x4  __attribute__((ext_vector_type(4)));
typedef unsigned short u16;

#define T_SEQ 2048
#define C_DIM 1024
#define NH 16
#define HS 64
#define S_SETS 1023
#define S_PAD 1024
#define SCALE 0.125f     // 1/sqrt(64)
#define NEG_BIG -1e30f

__device__ __forceinline__ float bf2f(u16 u) {
    unsigned int x = ((unsigned int)u) << 16;
    return __builtin_bit_cast(float, x);
}
__device__ __forceinline__ u16 f2bf(float f) {
    unsigned int x = __builtin_bit_cast(unsigned int, f);
    unsigned int r = (x + 0x7FFFu + ((x >> 16) & 1u)) >> 16;
    return (u16)r;
}
__device__ __forceinline__ f32x4 mfma16(bf16x8 a, bf16x8 b, f32x4 c) {
    return __builtin_amdgcn_mfma_f32_16x16x32_bf16(a, b, c, 0, 0, 0);
}

// -------- Kernel 0a: fp32 -> (hi, lo) bf16 split ----------------------------
__global__ __launch_bounds__(256) void conv_split(const float* __restrict__ in,
                                                  u16* __restrict__ hi,
                                                  u16* __restrict__ lo, int n4) {
    int i = blockIdx.x * 256 + threadIdx.x;
    if (i >= n4) return;
    float4 f = ((const float4*)in)[i];
    ushort4 h, l;
    h.x = f2bf(f.x); l.x = f2bf(f.x - bf2f(h.x));
    h.y = f2bf(f.y); l.y = f2bf(f.y - bf2f(h.y));
    h.z = f2bf(f.z); l.z = f2bf(f.z - bf2f(h.z));
    h.w = f2bf(f.w); l.w = f2bf(f.w - bf2f(h.w));
    ((ushort4*)hi)[i] = h;
    ((ushort4*)lo)[i] = l;
}

// -------- Kernel 0b: fp32 -> bf16 (plain) -----------------------------------
__global__ __launch_bounds__(256) void conv_plain(const float* __restrict__ in,
                                                  u16* __restrict__ out, int n4) {
    int i = blockIdx.x * 256 + threadIdx.x;
    if (i >= n4) return;
    float4 f = ((const float4*)in)[i];
    ushort4 o;
    o.x = f2bf(f.x); o.y = f2bf(f.y); o.z = f2bf(f.z); o.w = f2bf(f.w);
    ((ushort4*)out)[i] = o;
}

// -------- Kernel 1: qkv = x @ W_attn^T, split-bf16 (fp32-grade) -------------
// q written as bf16 hi/lo pair; k,v fp32 (for set sums + tails).
__global__ __launch_bounds__(256) void gemm_qkv3(const u16* __restrict__ xh,
                                                 const u16* __restrict__ xl,
                                                 const u16* __restrict__ wh,
                                                 const u16* __restrict__ wl,
                                                 u16* __restrict__ qh,
                                                 u16* __restrict__ ql,
                                                 float* __restrict__ kf,
                                                 float* __restrict__ vf) {
    int wid  = blockIdx.x * 4 + (threadIdx.x >> 6);
    int lane = threadIdx.x & 63;
    int lm = lane & 15, quad = lane >> 4;
    int nt = wid % 192, mt = wid / 192;
    size_t aoff = (size_t)(mt * 16 + lm) * C_DIM + quad * 8;
    size_t boff = (size_t)(nt * 16 + lm) * C_DIM + quad * 8;
    const u16* xhr = xh + aoff; const u16* xlr = xl + aoff;
    const u16* whr = wh + boff; const u16* wlr = wl + boff;
    f32x4 acc = {0.f, 0.f, 0.f, 0.f};
    for (int k = 0; k < C_DIM; k += 32) {
        bf16x8 ah = *(const bf16x8*)(xhr + k);
        bf16x8 al = *(const bf16x8*)(xlr + k);
        bf16x8 bh = *(const bf16x8*)(whr + k);
        bf16x8 bl = *(const bf16x8*)(wlr + k);
        acc = mfma16(ah, bh, acc);
        acc = mfma16(ah, bl, acc);
        acc = mfma16(al, bh, acc);
    }
    int n = nt * 16 + lm;
    int which = n >> 10, h = (n >> 6) & 15, d = n & 63;
    for (int reg = 0; reg < 4; ++reg) {
        int m = mt * 16 + quad * 4 + reg;
        int b_ = m >> 11, t = m & 2047;
        size_t oi = (((size_t)(b_ * NH + h)) * T_SEQ + t) * HS + d;
        float val = acc[reg];
        if (which == 0) {
            u16 hh = f2bf(val);
            qh[oi] = hh;
            ql[oi] = f2bf(val - bf2f(hh));
        }
        else if (which == 1) kf[oi] = val;
        else                 vf[oi] = val;
    }
}

// -------- Kernel 2: hierarchical set sums -> split-bf16 outputs -------------
// Block per (bh, src, dc). Kh/Kl s-major [bh][s][d]; VhT/VlT d-major
// [bh][d][s] (stride S_PAD). fp32 tree in LDS.
__global__ __launch_bounds__(256) void set_sums(const float* __restrict__ kf,
                                                const float* __restrict__ vf,
                                                u16* __restrict__ Kh,
                                                u16* __restrict__ Kl,
                                                u16* __restrict__ VhT,
                                                u16* __restrict__ VlT) {
    int bh  = blockIdx.x;
    int src = blockIdx.y >> 2;
    int dc  = blockIdx.y & 3;
    int tid = threadIdx.x;
    __shared__ float lv0[512 * 16];
    __shared__ float lv1[256 * 16];
    const float* sp = src ? vf : kf;
    u16* oh = src ? VhT : Kh;
    u16* ol = src ? VlT : Kl;
    int dbase = dc * 16;
    for (int idx = tid; idx < 512 * 16; idx += 256) {
        int sg = idx >> 4, dd = idx & 15, d = dbase + dd;
        const float* p = sp + ((size_t)bh * T_SEQ + sg * 4) * HS + d;
        float s = p[0] + p[HS] + p[2 * HS] + p[3 * HS];
        lv0[sg * 16 + dd] = s;
        u16 h = f2bf(s); u16 l = f2bf(s - bf2f(h));
        size_t o = src ? ((size_t)bh * HS + d) * S_PAD + sg
                       : ((size_t)bh * S_PAD + sg) * HS + d;
        oh[o] = h; ol[o] = l;
    }
    __syncthreads();
    int nsets = 256, offset = 512, lvl = 1;
    while (nsets >= 1) {
        float* sbuf = (lvl & 1) ? lv0 : lv1;
        float* dbuf = (lvl & 1) ? lv1 : lv0;
        for (int idx = tid; idx < nsets * 16; idx += 256) {
            int i = idx >> 4, dd = idx & 15, d = dbase + dd;
            float s = sbuf[(2 * i) * 16 + dd] + sbuf[(2 * i + 1) * 16 + dd];
            dbuf[i * 16 + dd] = s;
            int so = offset + i;
            u16 h = f2bf(s); u16 l = f2bf(s - bf2f(h));
            size_t o = src ? ((size_t)bh * HS + d) * S_PAD + so
                           : ((size_t)bh * S_PAD + so) * HS + d;
            oh[o] = h; ol[o] = l;
        }
        __syncthreads();
        offset += nsets; nsets >>= 1; lvl++;
    }
}

// -------- Kernel 3: attention, MFMA with precision splits -------------------
// Phase1: logits = q@K^T via split-bf16 MFMA (fp32-grade), fp32 in LDS.
// Phase2: fp32 softmax + tail (identical to validated R3/R6 code).
// Phase3: P(bf16) @ [Vh+Vl] MFMA in 128-set chunks. Epilogue adds tail V.
__global__ __launch_bounds__(256) void attn_mfma(const u16* __restrict__ qh,
                                                 const u16* __restrict__ ql,
                                                 const float* __restrict__ kf,
                                                 const float* __restrict__ vf,
                                                 const u16* __restrict__ Kh,
                                                 const u16* __restrict__ Kl,
                                                 const u16* __restrict__ VhT,
                                                 const u16* __restrict__ VlT,
                                                 u16* __restrict__ attout) {
    int bh = blockIdx.y;
    int t0 = blockIdx.x * 16;
    int tid = threadIdx.x, wv = tid >> 6, lane = tid & 63;
    int lm = lane & 15, quad = lane >> 4;
    __shared__ float lg[16][1032];   // fp32 logits -> normalized P (66KB)
    __shared__ u16 qsh[16 * 72];     // q hi tile, padded stride 72 (2-way banks)
    __shared__ u16 qsl[16 * 72];     // q lo tile
    __shared__ u16 pchunk[16 * 136]; // P bf16 staging, padded stride 136
    __shared__ float ptl[16];        // normalized tail prob

    // phase 0: stage q tiles (16 x 64 bf16 hi/lo)
    {
        const u16* gh = qh + ((size_t)bh * T_SEQ + t0) * HS;
        const u16* gl = ql + ((size_t)bh * T_SEQ + t0) * HS;
        int r = tid >> 4, c4 = (tid & 15) * 4;  // 256 threads x 4 elems
        *(ushort4*)(qsh + r * 72 + c4) = *(const ushort4*)(gh + r * 64 + c4);
        *(ushort4*)(qsl + r * 72 + c4) = *(const ushort4*)(gl + r * 64 + c4);
    }
    __syncthreads();

    // phase 1: logits via split MFMA (qh*Kh + qh*Kl + ql*Kh)
    bf16x8 ah0 = *(const bf16x8*)(qsh + lm * 72 + quad * 8);
    bf16x8 ah1 = *(const bf16x8*)(qsh + lm * 72 + 32 + quad * 8);
    bf16x8 al0 = *(const bf16x8*)(qsl + lm * 72 + quad * 8);
    bf16x8 al1 = *(const bf16x8*)(qsl + lm * 72 + 32 + quad * 8);
    for (int j = 0; j < 16; ++j) {
        int s = (wv + j * 4) * 16 + lm;
        const u16* krh = Kh + ((size_t)bh * S_PAD + s) * HS;
        const u16* krl = Kl + ((size_t)bh * S_PAD + s) * HS;
        bf16x8 bh0 = *(const bf16x8*)(krh + quad * 8);
        bf16x8 bh1 = *(const bf16x8*)(krh + 32 + quad * 8);
        bf16x8 bl0 = *(const bf16x8*)(krl + quad * 8);
        bf16x8 bl1 = *(const bf16x8*)(krl + 32 + quad * 8);
        f32x4 acc = {0.f, 0.f, 0.f, 0.f};
        acc = mfma16(ah0, bh0, acc);
        acc = mfma16(ah0, bl0, acc);
        acc = mfma16(al0, bh0, acc);
        acc = mfma16(ah1, bh1, acc);
        acc = mfma16(ah1, bl1, acc);
        acc = mfma16(al1, bh1, acc);
        int r = 0;
        bool sval = (s < S_SETS);
        if (sval) {
            int e = S_SETS - s;
            int l = __clz(e) - 22;              // level: L = 4<<l
            int i0 = s - (1024 - (1024 >> l));
            r = (i0 + 1) * (4 << l) - 1;
        }
        for (int reg = 0; reg < 4; ++reg) {
            int row = quad * 4 + reg;
            float val = (sval && (t0 + row) >= r) ? acc[reg] * SCALE : NEG_BIG;
            lg[row][s] = val;
        }
    }
    __syncthreads();

    // phase 2: softmax (validated fp32 path) — wave wv owns rows wv*4..+3
    for (int rr = 0; rr < 4; ++rr) {
        int r_ = wv * 4 + rr;
        int t = t0 + r_;
        float v[16], mx = NEG_BIG;
        for (int j = 0; j < 16; ++j) { v[j] = lg[r_][lane + j * 64]; mx = fmaxf(mx, v[j]); }
        for (int off = 32; off; off >>= 1) mx = fmaxf(mx, __shfl_xor(mx, off));
        // tail logit (lane = d)
        int len = (t & 3) + 1;
        const float* kp = kf + ((size_t)bh * T_SEQ + t) * HS + lane;
        float kt = 0.f;
        for (int j2 = 0; j2 < len; ++j2) kt += kp[-(j2 * HS)];
        float qv = bf2f(qsh[r_ * 72 + lane]) + bf2f(qsl[r_ * 72 + lane]);
        float tl = qv * kt;
        for (int off = 32; off; off >>= 1) tl += __shfl_xor(tl, off);
        tl *= SCALE;
        float Mx = fmaxf(mx, tl);
        float sm = 0.f;
        for (int j = 0; j < 16; ++j) { v[j] = __expf(v[j] - Mx); sm += v[j]; }
        for (int off = 32; off; off >>= 1) sm += __shfl_xor(sm, off);
        float pt = __expf(tl - Mx);
        float inv = 1.0f / (sm + pt);
        for (int j = 0; j < 16; ++j) lg[r_][lane + j * 64] = v[j] * inv;
        if (lane == 0) ptl[r_] = pt * inv;
    }
    __syncthreads();

    // phase 3: out = P @ Vsets, 8 chunks of 128 sets; wave wv owns d-tile
    int d = wv * 16 + lm;
    const u16* vrh = VhT + ((size_t)bh * HS + d) * S_PAD;
    const u16* vrl = VlT + ((size_t)bh * HS + d) * S_PAD;
    f32x4 acc = {0.f, 0.f, 0.f, 0.f};
    for (int chunk = 0; chunk < 8; ++chunk) {
        for (int i = tid; i < 2048; i += 256) {
            int r = i >> 7, c = i & 127;
            pchunk[r * 136 + c] = f2bf(lg[r][chunk * 128 + c]);
        }
        __syncthreads();
        for (int kc = 0; kc < 4; ++kc) {
            int kb = chunk * 128 + kc * 32 + quad * 8;
            bf16x8 a  = *(const bf16x8*)(pchunk + lm * 136 + kc * 32 + quad * 8);
            bf16x8 bh = *(const bf16x8*)(vrh + kb);
            bf16x8 bl = *(const bf16x8*)(vrl + kb);
            acc = mfma16(a, bh, acc);
            acc = mfma16(a, bl, acc);
        }
        __syncthreads();
    }

    // epilogue: + p_tail * V_tail, write bf16
    int b_ = bh >> 4, h_ = bh & 15;
    for (int reg = 0; reg < 4; ++reg) {
        int row = quad * 4 + reg;
        int t = t0 + row;
        int len = (t & 3) + 1;
        const float* vp = vf + ((size_t)bh * T_SEQ + t) * HS + d;
        float vt = 0.f;
        for (int j2 = 0; j2 < len; ++j2) vt += vp[-(j2 * HS)];
        float val = acc[reg] + ptl[row] * vt;
        attout[((size_t)(b_ * T_SEQ + t)) * C_DIM + h_ * HS + d] = f2bf(val);
    }
}

// -------- Kernel 4: out = attout @ W_proj^T (bf16 MFMA, fp32 OUT) -----------
__global__ __launch_bounds__(256) void gemm_proj(const u16* __restrict__ a_,
                                                 const u16* __restrict__ w,
                                                 float* __restrict__ out) {
    int wid  = blockIdx.x * 4 + (threadIdx.x >> 6);
    int lane = threadIdx.x & 63;
    int lm = lane & 15, quad = lane >> 4;
    int nt = wid & 63, mt = wid >> 6;
    const u16* ar = a_ + (size_t)(mt * 16 + lm) * C_DIM + quad * 8;
    const u16* wr = w + (size_t)(nt * 16 + lm) * C_DIM + quad * 8;
    f32x4 acc = {0.f, 0.f, 0.f, 0.f};
    for (int k = 0; k < C_DIM; k += 32) {
        bf16x8 a = *(const bf16x8*)(ar + k);
        bf16x8 b = *(const bf16x8*)(wr + k);
        acc = mfma16(a, b, acc);
    }
    int n = nt * 16 + lm;
    for (int reg = 0; reg < 4; ++reg) {
        int m = mt * 16 + quad * 4 + reg;
        out[(size_t)m * C_DIM + n] = acc[reg];   // fp32 output
    }
}

extern "C" void kernel_launch(void* const* d_in, const int* in_sizes, int n_in,
                              void* d_out, int out_size, void* d_ws, size_t ws_size,
                              hipStream_t stream) {
    const float* x     = (const float*)d_in[0];
    const float* Wattn = (const float*)d_in[1];
    const float* Wproj = (const float*)d_in[2];
    float* out = (float*)d_out;
    char* ws = (char*)d_ws;
    // workspace layout (78 MB, dead-buffer overlays)
    u16*   xh  = (u16*)(ws + 0);            //  8,388,608
    u16*   xl  = (u16*)(ws + 8388608);      //  8,388,608
    u16*   wh  = (u16*)(ws + 16777216);     //  6,291,456
    u16*   wl  = (u16*)(ws + 23068672);     //  6,291,456
    u16*   wp  = (u16*)(ws + 29360128);     //  2,097,152
    u16*   qh  = (u16*)(ws + 31457280);     //  8,388,608
    u16*   ql  = (u16*)(ws + 39845888);     //  8,388,608
    float* kf  = (float*)(ws + 48234496);   // 16,777,216
    float* vf  = (float*)(ws + 65011712);   // 16,777,216  (end 81,788,928)
    // overlays (xh/xl/wh/wl dead after gemm_qkv3)
    u16* Kh     = (u16*)(ws + 0);           //  4,194,304
    u16* Kl     = (u16*)(ws + 4194304);     //  4,194,304
    u16* VhT    = (u16*)(ws + 8388608);     //  4,194,304
    u16* VlT    = (u16*)(ws + 12582912);    //  4,194,304
    u16* attout = (u16*)(ws + 16777216);    //  8,388,608 (over wh/wl, ends < wp)

    hipLaunchKernelGGL(conv_split, dim3(4096), dim3(256), 0, stream, x, xh, xl, 1048576);
    hipLaunchKernelGGL(conv_split, dim3(3072), dim3(256), 0, stream, Wattn, wh, wl, 786432);
    hipLaunchKernelGGL(conv_plain, dim3(1024), dim3(256), 0, stream, Wproj, wp, 262144);
    hipLaunchKernelGGL(gemm_qkv3, dim3(12288), dim3(256), 0, stream, xh, xl, wh, wl, qh, ql, kf, vf);
    hipLaunchKernelGGL(set_sums, dim3(32, 8), dim3(256), 0, stream, kf, vf, Kh, Kl, VhT, VlT);
    hipLaunchKernelGGL(attn_mfma, dim3(128, 32), dim3(256), 0, stream,
                       qh, ql, kf, vf, Kh, Kl, VhT, VlT, attout);
    hipLaunchKernelGGL(gemm_proj, dim3(4096), dim3(256), 0, stream, attout, wp, out);
}

// Round 8
// 466.738 us; speedup vs baseline: 5.0318x; 2.4685x over previous
//
#include <hip/hip_runtime.h>

typedef short bf16x8 __attribute__((ext_vector_type(8)));
typedef float f32x4  __attribute__((ext_vector_type(4)));
typedef unsigned short u16;

#define T_SEQ 2048
#define C_DIM 1024
#define NH 16
#define HS 64
#define S_SETS 1023
#define S_PAD 1024
#define SCALE 0.125f     // 1/sqrt(64)
#define NEG_BIG -1e30f

#define GLB(p) ((const __attribute__((address_space(1))) void*)(p))
#define LDS(p) ((__attribute__((address_space(3))) void*)(p))

__device__ __forceinline__ float bf2f(u16 u) {
    unsigned int x = ((unsigned int)u) << 16;
    return __builtin_bit_cast(float, x);
}
__device__ __forceinline__ u16 f2bf(float f) {
    unsigned int x = __builtin_bit_cast(unsigned int, f);
    unsigned int r = (x + 0x7FFFu + ((x >> 16) & 1u)) >> 16;
    return (u16)r;
}
__device__ __forceinline__ f32x4 mfma16(bf16x8 a, bf16x8 b, f32x4 c) {
    return __builtin_amdgcn_mfma_f32_16x16x32_bf16(a, b, c, 0, 0, 0);
}

// -------- Kernel 0a: fp32 -> (hi, lo) bf16 split ----------------------------
__global__ __launch_bounds__(256) void conv_split(const float* __restrict__ in,
                                                  u16* __restrict__ hi,
                                                  u16* __restrict__ lo, int n4) {
    int i = blockIdx.x * 256 + threadIdx.x;
    if (i >= n4) return;
    float4 f = ((const float4*)in)[i];
    ushort4 h, l;
    h.x = f2bf(f.x); l.x = f2bf(f.x - bf2f(h.x));
    h.y = f2bf(f.y); l.y = f2bf(f.y - bf2f(h.y));
    h.z = f2bf(f.z); l.z = f2bf(f.z - bf2f(h.z));
    h.w = f2bf(f.w); l.w = f2bf(f.w - bf2f(h.w));
    ((ushort4*)hi)[i] = h;
    ((ushort4*)lo)[i] = l;
}

// -------- Kernel 0b: fp32 -> bf16 (plain) -----------------------------------
__global__ __launch_bounds__(256) void conv_plain(const float* __restrict__ in,
                                                  u16* __restrict__ out, int n4) {
    int i = blockIdx.x * 256 + threadIdx.x;
    if (i >= n4) return;
    float4 f = ((const float4*)in)[i];
    ushort4 o;
    o.x = f2bf(f.x); o.y = f2bf(f.y); o.z = f2bf(f.z); o.w = f2bf(f.w);
    ((ushort4*)out)[i] = o;
}

// -------- Kernel 1: qkv GEMM, m97-style 128x128 tile, split-bf16 ------------
// M=4096, N=3072, K=1024. Block = 4 waves, each 64x64 (4x4 16x16x32 MFMAs).
// LDS: Ah/Al/Bh/Bl 128x32 bf16 (8KB each). Stage via global_load_lds w=16.
__global__ __launch_bounds__(256) void gemm_qkv3_t(const u16* __restrict__ xh,
                                                   const u16* __restrict__ xl,
                                                   const u16* __restrict__ wh,
                                                   const u16* __restrict__ wl,
                                                   u16* __restrict__ qh,
                                                   u16* __restrict__ ql,
                                                   float* __restrict__ kf,
                                                   float* __restrict__ vf) {
    __shared__ u16 As[2][128 * 32];   // [0]=hi, [1]=lo
    __shared__ u16 Bs[2][128 * 32];
    int tid = threadIdx.x, wv = tid >> 6, lane = tid & 63;
    int lm = lane & 15, quad = lane >> 4;
    int mt = blockIdx.x / 24, nt = blockIdx.x % 24;
    int wm = wv >> 1, wn = wv & 1;            // wave 64x64 subtile
    int m_off = wm * 64, n_off = wn * 64;

    // staging source for this wave (wave stages one 8KB buffer)
    const u16* gsrc;
    u16* ldst;
    if      (wv == 0) { gsrc = xh + (size_t)(mt * 128) * C_DIM; ldst = As[0]; }
    else if (wv == 1) { gsrc = xl + (size_t)(mt * 128) * C_DIM; ldst = As[1]; }
    else if (wv == 2) { gsrc = wh + (size_t)(nt * 128) * C_DIM; ldst = Bs[0]; }
    else              { gsrc = wl + (size_t)(nt * 128) * C_DIM; ldst = Bs[1]; }
    int srow = lane >> 2, scol = (lane & 3) * 8;   // 16 rows / instr

    f32x4 acc[4][4];
    #pragma unroll
    for (int i = 0; i < 4; ++i)
        #pragma unroll
        for (int j = 0; j < 4; ++j) acc[i][j] = (f32x4){0.f, 0.f, 0.f, 0.f};

    for (int k0 = 0; k0 < C_DIM; k0 += 32) {
        __syncthreads();   // previous-iter LDS reads complete
        #pragma unroll
        for (int i = 0; i < 8; ++i) {
            int row = i * 16 + srow;
            __builtin_amdgcn_global_load_lds(
                GLB(gsrc + (size_t)row * C_DIM + k0 + scol),
                LDS(ldst + i * 512), 16, 0, 0);
        }
        __syncthreads();   // staging visible (compiler drains vmcnt)
        bf16x8 ah[4], al[4], bh[4], bl[4];
        #pragma unroll
        for (int i = 0; i < 4; ++i) {
            int ar = (m_off + i * 16 + lm) * 32 + quad * 8;
            int br = (n_off + i * 16 + lm) * 32 + quad * 8;
            ah[i] = *(const bf16x8*)(As[0] + ar);
            al[i] = *(const bf16x8*)(As[1] + ar);
            bh[i] = *(const bf16x8*)(Bs[0] + br);
            bl[i] = *(const bf16x8*)(Bs[1] + br);
        }
        #pragma unroll
        for (int mi = 0; mi < 4; ++mi)
            #pragma unroll
            for (int ni = 0; ni < 4; ++ni) {
                acc[mi][ni] = mfma16(ah[mi], bh[ni], acc[mi][ni]);
                acc[mi][ni] = mfma16(ah[mi], bl[ni], acc[mi][ni]);
                acc[mi][ni] = mfma16(al[mi], bh[ni], acc[mi][ni]);
            }
    }

    // epilogue: n -> (which, h, d); m -> (b, t)
    #pragma unroll
    for (int mi = 0; mi < 4; ++mi)
        #pragma unroll
        for (int ni = 0; ni < 4; ++ni) {
            int n = nt * 128 + n_off + ni * 16 + lm;
            int h = (n >> 6) & 15, d = n & 63;
            #pragma unroll
            for (int reg = 0; reg < 4; ++reg) {
                int m = mt * 128 + m_off + mi * 16 + quad * 4 + reg;
                int b_ = m >> 11, t = m & 2047;
                size_t oi = (((size_t)(b_ * NH + h)) * T_SEQ + t) * HS + d;
                float val = acc[mi][ni][reg];
                if (nt < 8) {
                    u16 hh = f2bf(val);
                    qh[oi] = hh;
                    ql[oi] = f2bf(val - bf2f(hh));
                } else if (nt < 16) kf[oi] = val;
                else                vf[oi] = val;
            }
        }
}

// -------- Kernel 2: hierarchical set sums -> split-bf16 outputs -------------
__global__ __launch_bounds__(256) void set_sums(const float* __restrict__ kf,
                                                const float* __restrict__ vf,
                                                u16* __restrict__ Kh,
                                                u16* __restrict__ Kl,
                                                u16* __restrict__ VhT,
                                                u16* __restrict__ VlT) {
    int bh  = blockIdx.x;
    int src = blockIdx.y >> 2;
    int dc  = blockIdx.y & 3;
    int tid = threadIdx.x;
    __shared__ float lv0[512 * 16];
    __shared__ float lv1[256 * 16];
    const float* sp = src ? vf : kf;
    u16* oh = src ? VhT : Kh;
    u16* ol = src ? VlT : Kl;
    int dbase = dc * 16;
    for (int idx = tid; idx < 512 * 16; idx += 256) {
        int sg = idx >> 4, dd = idx & 15, d = dbase + dd;
        const float* p = sp + ((size_t)bh * T_SEQ + sg * 4) * HS + d;
        float s = p[0] + p[HS] + p[2 * HS] + p[3 * HS];
        lv0[sg * 16 + dd] = s;
        u16 h = f2bf(s); u16 l = f2bf(s - bf2f(h));
        size_t o = src ? ((size_t)bh * HS + d) * S_PAD + sg
                       : ((size_t)bh * S_PAD + sg) * HS + d;
        oh[o] = h; ol[o] = l;
    }
    __syncthreads();
    int nsets = 256, offset = 512, lvl = 1;
    while (nsets >= 1) {
        float* sbuf = (lvl & 1) ? lv0 : lv1;
        float* dbuf = (lvl & 1) ? lv1 : lv0;
        for (int idx = tid; idx < nsets * 16; idx += 256) {
            int i = idx >> 4, dd = idx & 15, d = dbase + dd;
            float s = sbuf[(2 * i) * 16 + dd] + sbuf[(2 * i + 1) * 16 + dd];
            dbuf[i * 16 + dd] = s;
            int so = offset + i;
            u16 h = f2bf(s); u16 l = f2bf(s - bf2f(h));
            size_t o = src ? ((size_t)bh * HS + d) * S_PAD + so
                           : ((size_t)bh * S_PAD + so) * HS + d;
            oh[o] = h; ol[o] = l;
        }
        __syncthreads();
        offset += nsets; nsets >>= 1; lvl++;
    }
}

// -------- Kernel 3: attention, MFMA with precision splits (unchanged) -------
__global__ __launch_bounds__(256) void attn_mfma(const u16* __restrict__ qh,
                                                 const u16* __restrict__ ql,
                                                 const float* __restrict__ kf,
                                                 const float* __restrict__ vf,
                                                 const u16* __restrict__ Kh,
                                                 const u16* __restrict__ Kl,
                                                 const u16* __restrict__ VhT,
                                                 const u16* __restrict__ VlT,
                                                 u16* __restrict__ attout) {
    int bh = blockIdx.y;
    int t0 = blockIdx.x * 16;
    int tid = threadIdx.x, wv = tid >> 6, lane = tid & 63;
    int lm = lane & 15, quad = lane >> 4;
    __shared__ float lg[16][1032];
    __shared__ u16 qsh[16 * 72];
    __shared__ u16 qsl[16 * 72];
    __shared__ u16 pchunk[16 * 136];
    __shared__ float ptl[16];

    {
        const u16* gh = qh + ((size_t)bh * T_SEQ + t0) * HS;
        const u16* gl = ql + ((size_t)bh * T_SEQ + t0) * HS;
        int r = tid >> 4, c4 = (tid & 15) * 4;
        *(ushort4*)(qsh + r * 72 + c4) = *(const ushort4*)(gh + r * 64 + c4);
        *(ushort4*)(qsl + r * 72 + c4) = *(const ushort4*)(gl + r * 64 + c4);
    }
    __syncthreads();

    bf16x8 ah0 = *(const bf16x8*)(qsh + lm * 72 + quad * 8);
    bf16x8 ah1 = *(const bf16x8*)(qsh + lm * 72 + 32 + quad * 8);
    bf16x8 al0 = *(const bf16x8*)(qsl + lm * 72 + quad * 8);
    bf16x8 al1 = *(const bf16x8*)(qsl + lm * 72 + 32 + quad * 8);
    for (int j = 0; j < 16; ++j) {
        int s = (wv + j * 4) * 16 + lm;
        const u16* krh = Kh + ((size_t)bh * S_PAD + s) * HS;
        const u16* krl = Kl + ((size_t)bh * S_PAD + s) * HS;
        bf16x8 bh0 = *(const bf16x8*)(krh + quad * 8);
        bf16x8 bh1 = *(const bf16x8*)(krh + 32 + quad * 8);
        bf16x8 bl0 = *(const bf16x8*)(krl + quad * 8);
        bf16x8 bl1 = *(const bf16x8*)(krl + 32 + quad * 8);
        f32x4 acc = {0.f, 0.f, 0.f, 0.f};
        acc = mfma16(ah0, bh0, acc);
        acc = mfma16(ah0, bl0, acc);
        acc = mfma16(al0, bh0, acc);
        acc = mfma16(ah1, bh1, acc);
        acc = mfma16(ah1, bl1, acc);
        acc = mfma16(al1, bh1, acc);
        int r = 0;
        bool sval = (s < S_SETS);
        if (sval) {
            int e = S_SETS - s;
            int l = __clz(e) - 22;
            int i0 = s - (1024 - (1024 >> l));
            r = (i0 + 1) * (4 << l) - 1;
        }
        for (int reg = 0; reg < 4; ++reg) {
            int row = quad * 4 + reg;
            float val = (sval && (t0 + row) >= r) ? acc[reg] * SCALE : NEG_BIG;
            lg[row][s] = val;
        }
    }
    __syncthreads();

    for (int rr = 0; rr < 4; ++rr) {
        int r_ = wv * 4 + rr;
        int t = t0 + r_;
        float v[16], mx = NEG_BIG;
        for (int j = 0; j < 16; ++j) { v[j] = lg[r_][lane + j * 64]; mx = fmaxf(mx, v[j]); }
        for (int off = 32; off; off >>= 1) mx = fmaxf(mx, __shfl_xor(mx, off));
        int len = (t & 3) + 1;
        const float* kp = kf + ((size_t)bh * T_SEQ + t) * HS + lane;
        float kt = 0.f;
        for (int j2 = 0; j2 < len; ++j2) kt += kp[-(j2 * HS)];
        float qv = bf2f(qsh[r_ * 72 + lane]) + bf2f(qsl[r_ * 72 + lane]);
        float tl = qv * kt;
        for (int off = 32; off; off >>= 1) tl += __shfl_xor(tl, off);
        tl *= SCALE;
        float Mx = fmaxf(mx, tl);
        float sm = 0.f;
        for (int j = 0; j < 16; ++j) { v[j] = __expf(v[j] - Mx); sm += v[j]; }
        for (int off = 32; off; off >>= 1) sm += __shfl_xor(sm, off);
        float pt = __expf(tl - Mx);
        float inv = 1.0f / (sm + pt);
        for (int j = 0; j < 16; ++j) lg[r_][lane + j * 64] = v[j] * inv;
        if (lane == 0) ptl[r_] = pt * inv;
    }
    __syncthreads();

    int d = wv * 16 + lm;
    const u16* vrh = VhT + ((size_t)bh * HS + d) * S_PAD;
    const u16* vrl = VlT + ((size_t)bh * HS + d) * S_PAD;
    f32x4 acc = {0.f, 0.f, 0.f, 0.f};
    for (int chunk = 0; chunk < 8; ++chunk) {
        for (int i = tid; i < 2048; i += 256) {
            int r = i >> 7, c = i & 127;
            pchunk[r * 136 + c] = f2bf(lg[r][chunk * 128 + c]);
        }
        __syncthreads();
        for (int kc = 0; kc < 4; ++kc) {
            int kb = chunk * 128 + kc * 32 + quad * 8;
            bf16x8 a  = *(const bf16x8*)(pchunk + lm * 136 + kc * 32 + quad * 8);
            bf16x8 bh = *(const bf16x8*)(vrh + kb);
            bf16x8 bl = *(const bf16x8*)(vrl + kb);
            acc = mfma16(a, bh, acc);
            acc = mfma16(a, bl, acc);
        }
        __syncthreads();
    }

    int b_ = bh >> 4, h_ = bh & 15;
    for (int reg = 0; reg < 4; ++reg) {
        int row = quad * 4 + reg;
        int t = t0 + row;
        int len = (t & 3) + 1;
        const float* vp = vf + ((size_t)bh * T_SEQ + t) * HS + d;
        float vt = 0.f;
        for (int j2 = 0; j2 < len; ++j2) vt += vp[-(j2 * HS)];
        float val = acc[reg] + ptl[row] * vt;
        attout[((size_t)(b_ * T_SEQ + t)) * C_DIM + h_ * HS + d] = f2bf(val);
    }
}

// -------- Kernel 4: proj GEMM, m97-style 128x128 tile, plain bf16 -----------
// M=4096, N=1024, K=1024. fp32 output (d_out).
__global__ __launch_bounds__(256) void gemm_proj_t(const u16* __restrict__ a_,
                                                   const u16* __restrict__ w,
                                                   float* __restrict__ out) {
    __shared__ u16 As[128 * 32];
    __shared__ u16 Bs[128 * 32];
    int tid = threadIdx.x, wv = tid >> 6, lane = tid & 63;
    int lm = lane & 15, quad = lane >> 4;
    int mt = blockIdx.x >> 3, nt = blockIdx.x & 7;
    int wm = wv >> 1, wn = wv & 1;
    int m_off = wm * 64, n_off = wn * 64;

    // wave 0/1 stage A halves; wave 2/3 stage B halves (4 instr each)
    const u16* gsrc;
    u16* ldst;
    int half = wv & 1;
    if (wv < 2) { gsrc = a_ + (size_t)(mt * 128 + half * 64) * C_DIM; ldst = As + half * 64 * 32; }
    else        { gsrc = w  + (size_t)(nt * 128 + half * 64) * C_DIM; ldst = Bs + half * 64 * 32; }
    int srow = lane >> 2, scol = (lane & 3) * 8;

    f32x4 acc[4][4];
    #pragma unroll
    for (int i = 0; i < 4; ++i)
        #pragma unroll
        for (int j = 0; j < 4; ++j) acc[i][j] = (f32x4){0.f, 0.f, 0.f, 0.f};

    for (int k0 = 0; k0 < C_DIM; k0 += 32) {
        __syncthreads();
        #pragma unroll
        for (int i = 0; i < 4; ++i) {
            int row = i * 16 + srow;
            __builtin_amdgcn_global_load_lds(
                GLB(gsrc + (size_t)row * C_DIM + k0 + scol),
                LDS(ldst + i * 512), 16, 0, 0);
        }
        __syncthreads();
        bf16x8 af[4], bf[4];
        #pragma unroll
        for (int i = 0; i < 4; ++i) {
            af[i] = *(const bf16x8*)(As + (m_off + i * 16 + lm) * 32 + quad * 8);
            bf[i] = *(const bf16x8*)(Bs + (n_off + i * 16 + lm) * 32 + quad * 8);
        }
        #pragma unroll
        for (int mi = 0; mi < 4; ++mi)
            #pragma unroll
            for (int ni = 0; ni < 4; ++ni)
                acc[mi][ni] = mfma16(af[mi], bf[ni], acc[mi][ni]);
    }

    #pragma unroll
    for (int mi = 0; mi < 4; ++mi)
        #pragma unroll
        for (int ni = 0; ni < 4; ++ni) {
            int n = nt * 128 + n_off + ni * 16 + lm;
            #pragma unroll
            for (int reg = 0; reg < 4; ++reg) {
                int m = mt * 128 + m_off + mi * 16 + quad * 4 + reg;
                out[(size_t)m * C_DIM + n] = acc[mi][ni][reg];
            }
        }
}

extern "C" void kernel_launch(void* const* d_in, const int* in_sizes, int n_in,
                              void* d_out, int out_size, void* d_ws, size_t ws_size,
                              hipStream_t stream) {
    const float* x     = (const float*)d_in[0];
    const float* Wattn = (const float*)d_in[1];
    const float* Wproj = (const float*)d_in[2];
    float* out = (float*)d_out;
    char* ws = (char*)d_ws;
    // workspace layout (78 MB, dead-buffer overlays)
    u16*   xh  = (u16*)(ws + 0);            //  8,388,608
    u16*   xl  = (u16*)(ws + 8388608);      //  8,388,608
    u16*   wh  = (u16*)(ws + 16777216);     //  6,291,456
    u16*   wl  = (u16*)(ws + 23068672);     //  6,291,456
    u16*   wp  = (u16*)(ws + 29360128);     //  2,097,152
    u16*   qh  = (u16*)(ws + 31457280);     //  8,388,608
    u16*   ql  = (u16*)(ws + 39845888);     //  8,388,608
    float* kf  = (float*)(ws + 48234496);   // 16,777,216
    float* vf  = (float*)(ws + 65011712);   // 16,777,216  (end 81,788,928)
    // overlays (xh/xl/wh/wl dead after gemm_qkv3_t)
    u16* Kh     = (u16*)(ws + 0);           //  4,194,304
    u16* Kl     = (u16*)(ws + 4194304);     //  4,194,304
    u16* VhT    = (u16*)(ws + 8388608);     //  4,194,304
    u16* VlT    = (u16*)(ws + 12582912);    //  4,194,304
    u16* attout = (u16*)(ws + 16777216);    //  8,388,608 (over wh/wl, ends < wp)

    hipLaunchKernelGGL(conv_split, dim3(4096), dim3(256), 0, stream, x, xh, xl, 1048576);
    hipLaunchKernelGGL(conv_split, dim3(3072), dim3(256), 0, stream, Wattn, wh, wl, 786432);
    hipLaunchKernelGGL(conv_plain, dim3(1024), dim3(256), 0, stream, Wproj, wp, 262144);
    hipLaunchKernelGGL(gemm_qkv3_t, dim3(768), dim3(256), 0, stream, xh, xl, wh, wl, qh, ql, kf, vf);
    hipLaunchKernelGGL(set_sums, dim3(32, 8), dim3(256), 0, stream, kf, vf, Kh, Kl, VhT, VlT);
    hipLaunchKernelGGL(attn_mfma, dim3(128, 32), dim3(256), 0, stream,
                       qh, ql, kf, vf, Kh, Kl, VhT, VlT, attout);
    hipLaunchKernelGGL(gemm_proj_t, dim3(256), dim3(256), 0, stream, attout, wp, out);
}

// Round 9
// 371.495 us; speedup vs baseline: 6.3218x; 1.2564x over previous
//
#include <hip/hip_runtime.h>

typedef short bf16x8 __attribute__((ext_vector_type(8)));
typedef unsigned short u16x8 __attribute__((ext_vector_type(8)));
typedef float f32x4  __attribute__((ext_vector_type(4)));
typedef unsigned short u16;

#define T_SEQ 2048
#define C_DIM 1024
#define NH 16
#define HS 64
#define S_SETS 1023
#define S_PAD 1024
#define SCALE 0.125f     // 1/sqrt(64)
#define NEG_BIG -1e30f

#define GLB(p) ((const __attribute__((address_space(1))) void*)(p))
#define LDS(p) ((__attribute__((address_space(3))) void*)(p))

__device__ __forceinline__ float bf2f(u16 u) {
    unsigned int x = ((unsigned int)u) << 16;
    return __builtin_bit_cast(float, x);
}
__device__ __forceinline__ u16 f2bf(float f) {
    unsigned int x = __builtin_bit_cast(unsigned int, f);
    unsigned int r = (x + 0x7FFFu + ((x >> 16) & 1u)) >> 16;
    return (u16)r;
}
__device__ __forceinline__ f32x4 mfma16(bf16x8 a, bf16x8 b, f32x4 c) {
    return __builtin_amdgcn_mfma_f32_16x16x32_bf16(a, b, c, 0, 0, 0);
}

// -------- Kernel 0a: fp32 -> (hi, lo) bf16 split ----------------------------
__global__ __launch_bounds__(256) void conv_split(const float* __restrict__ in,
                                                  u16* __restrict__ hi,
                                                  u16* __restrict__ lo, int n4) {
    int i = blockIdx.x * 256 + threadIdx.x;
    if (i >= n4) return;
    float4 f = ((const float4*)in)[i];
    ushort4 h, l;
    h.x = f2bf(f.x); l.x = f2bf(f.x - bf2f(h.x));
    h.y = f2bf(f.y); l.y = f2bf(f.y - bf2f(h.y));
    h.z = f2bf(f.z); l.z = f2bf(f.z - bf2f(h.z));
    h.w = f2bf(f.w); l.w = f2bf(f.w - bf2f(h.w));
    ((ushort4*)hi)[i] = h;
    ((ushort4*)lo)[i] = l;
}

// -------- Kernel 0b: fp32 -> bf16 (plain) -----------------------------------
__global__ __launch_bounds__(256) void conv_plain(const float* __restrict__ in,
                                                  u16* __restrict__ out, int n4) {
    int i = blockIdx.x * 256 + threadIdx.x;
    if (i >= n4) return;
    float4 f = ((const float4*)in)[i];
    ushort4 o;
    o.x = f2bf(f.x); o.y = f2bf(f.y); o.z = f2bf(f.z); o.w = f2bf(f.w);
    ((ushort4*)out)[i] = o;
}

// -------- Kernel 1: qkv GEMM, 128x128 tile, split-bf16 (unchanged R8) -------
__global__ __launch_bounds__(256) void gemm_qkv3_t(const u16* __restrict__ xh,
                                                   const u16* __restrict__ xl,
                                                   const u16* __restrict__ wh,
                                                   const u16* __restrict__ wl,
                                                   u16* __restrict__ qh,
                                                   u16* __restrict__ ql,
                                                   float* __restrict__ kf,
                                                   float* __restrict__ vf) {
    __shared__ u16 As[2][128 * 32];
    __shared__ u16 Bs[2][128 * 32];
    int tid = threadIdx.x, wv = tid >> 6, lane = tid & 63;
    int lm = lane & 15, quad = lane >> 4;
    int mt = blockIdx.x / 24, nt = blockIdx.x % 24;
    int wm = wv >> 1, wn = wv & 1;
    int m_off = wm * 64, n_off = wn * 64;

    const u16* gsrc;
    u16* ldst;
    if      (wv == 0) { gsrc = xh + (size_t)(mt * 128) * C_DIM; ldst = As[0]; }
    else if (wv == 1) { gsrc = xl + (size_t)(mt * 128) * C_DIM; ldst = As[1]; }
    else if (wv == 2) { gsrc = wh + (size_t)(nt * 128) * C_DIM; ldst = Bs[0]; }
    else              { gsrc = wl + (size_t)(nt * 128) * C_DIM; ldst = Bs[1]; }
    int srow = lane >> 2, scol = (lane & 3) * 8;

    f32x4 acc[4][4];
    #pragma unroll
    for (int i = 0; i < 4; ++i)
        #pragma unroll
        for (int j = 0; j < 4; ++j) acc[i][j] = (f32x4){0.f, 0.f, 0.f, 0.f};

    for (int k0 = 0; k0 < C_DIM; k0 += 32) {
        __syncthreads();
        #pragma unroll
        for (int i = 0; i < 8; ++i) {
            int row = i * 16 + srow;
            __builtin_amdgcn_global_load_lds(
                GLB(gsrc + (size_t)row * C_DIM + k0 + scol),
                LDS(ldst + i * 512), 16, 0, 0);
        }
        __syncthreads();
        bf16x8 ah[4], al[4], bh[4], bl[4];
        #pragma unroll
        for (int i = 0; i < 4; ++i) {
            int ar = (m_off + i * 16 + lm) * 32 + quad * 8;
            int br = (n_off + i * 16 + lm) * 32 + quad * 8;
            ah[i] = *(const bf16x8*)(As[0] + ar);
            al[i] = *(const bf16x8*)(As[1] + ar);
            bh[i] = *(const bf16x8*)(Bs[0] + br);
            bl[i] = *(const bf16x8*)(Bs[1] + br);
        }
        #pragma unroll
        for (int mi = 0; mi < 4; ++mi)
            #pragma unroll
            for (int ni = 0; ni < 4; ++ni) {
                acc[mi][ni] = mfma16(ah[mi], bh[ni], acc[mi][ni]);
                acc[mi][ni] = mfma16(ah[mi], bl[ni], acc[mi][ni]);
                acc[mi][ni] = mfma16(al[mi], bh[ni], acc[mi][ni]);
            }
    }

    #pragma unroll
    for (int mi = 0; mi < 4; ++mi)
        #pragma unroll
        for (int ni = 0; ni < 4; ++ni) {
            int n = nt * 128 + n_off + ni * 16 + lm;
            int h = (n >> 6) & 15, d = n & 63;
            #pragma unroll
            for (int reg = 0; reg < 4; ++reg) {
                int m = mt * 128 + m_off + mi * 16 + quad * 4 + reg;
                int b_ = m >> 11, t = m & 2047;
                size_t oi = (((size_t)(b_ * NH + h)) * T_SEQ + t) * HS + d;
                float val = acc[mi][ni][reg];
                if (nt < 8) {
                    u16 hh = f2bf(val);
                    qh[oi] = hh;
                    ql[oi] = f2bf(val - bf2f(hh));
                } else if (nt < 16) kf[oi] = val;
                else                vf[oi] = val;
            }
        }
}

// -------- Kernel 2: hierarchical set sums -> split-bf16 (unchanged R8) ------
__global__ __launch_bounds__(256) void set_sums(const float* __restrict__ kf,
                                                const float* __restrict__ vf,
                                                u16* __restrict__ Kh,
                                                u16* __restrict__ Kl,
                                                u16* __restrict__ VhT,
                                                u16* __restrict__ VlT) {
    int bh  = blockIdx.x;
    int src = blockIdx.y >> 2;
    int dc  = blockIdx.y & 3;
    int tid = threadIdx.x;
    __shared__ float lv0[512 * 16];
    __shared__ float lv1[256 * 16];
    const float* sp = src ? vf : kf;
    u16* oh = src ? VhT : Kh;
    u16* ol = src ? VlT : Kl;
    int dbase = dc * 16;
    for (int idx = tid; idx < 512 * 16; idx += 256) {
        int sg = idx >> 4, dd = idx & 15, d = dbase + dd;
        const float* p = sp + ((size_t)bh * T_SEQ + sg * 4) * HS + d;
        float s = p[0] + p[HS] + p[2 * HS] + p[3 * HS];
        lv0[sg * 16 + dd] = s;
        u16 h = f2bf(s); u16 l = f2bf(s - bf2f(h));
        size_t o = src ? ((size_t)bh * HS + d) * S_PAD + sg
                       : ((size_t)bh * S_PAD + sg) * HS + d;
        oh[o] = h; ol[o] = l;
    }
    __syncthreads();
    int nsets = 256, offset = 512, lvl = 1;
    while (nsets >= 1) {
        float* sbuf = (lvl & 1) ? lv0 : lv1;
        float* dbuf = (lvl & 1) ? lv1 : lv0;
        for (int idx = tid; idx < nsets * 16; idx += 256) {
            int i = idx >> 4, dd = idx & 15, d = dbase + dd;
            float s = sbuf[(2 * i) * 16 + dd] + sbuf[(2 * i + 1) * 16 + dd];
            dbuf[i * 16 + dd] = s;
            int so = offset + i;
            u16 h = f2bf(s); u16 l = f2bf(s - bf2f(h));
            size_t o = src ? ((size_t)bh * HS + d) * S_PAD + so
                           : ((size_t)bh * S_PAD + so) * HS + d;
            oh[o] = h; ol[o] = l;
        }
        __syncthreads();
        offset += nsets; nsets >>= 1; lvl++;
    }
}

// -------- Kernel 3: flash-style attention, 64 queries/block -----------------
// 4 waves; wave owns 16 queries. 8 chunks of 128 sets; online softmax in regs
// (C-layout: row=quad*4+reg=query, col=lm=set/d). K chunk staged in LDS with
// XOR swizzle; P via per-wave LDS buffer (C->A layout); V B-frags from L2.
__global__ __launch_bounds__(256) void attn_flash(const u16* __restrict__ qh,
                                                  const u16* __restrict__ ql,
                                                  const float* __restrict__ kf,
                                                  const float* __restrict__ vf,
                                                  const u16* __restrict__ Khg,
                                                  const u16* __restrict__ Klg,
                                                  const u16* __restrict__ VhT,
                                                  const u16* __restrict__ VlT,
                                                  u16* __restrict__ attout) {
    int bh = blockIdx.y;
    int t0 = blockIdx.x * 64;
    int tid = threadIdx.x, wv = tid >> 6, lane = tid & 63;
    int lm = lane & 15, quad = lane >> 4;
    int t0w = t0 + wv * 16;          // wave's first query row
    int twmax = t0w + 15;

    __shared__ u16 Ksh[128 * 64];    // K chunk hi, XOR-swizzled (16KB)
    __shared__ u16 Ksl[128 * 64];    // K chunk lo (16KB)
    __shared__ u16 Pbuf[4][16 * 136];// per-wave P (bf16, A-layout rows)
    __shared__ float ptl[4][16];     // per-wave tail logits

    // Q A-frags from global (once)
    const u16* qgh = qh + ((size_t)bh * T_SEQ + t0w + lm) * HS;
    const u16* qgl = ql + ((size_t)bh * T_SEQ + t0w + lm) * HS;
    bf16x8 ah0 = *(const bf16x8*)(qgh + quad * 8);
    bf16x8 ah1 = *(const bf16x8*)(qgh + 32 + quad * 8);
    bf16x8 al0 = *(const bf16x8*)(qgl + quad * 8);
    bf16x8 al1 = *(const bf16x8*)(qgl + 32 + quad * 8);

    f32x4 O[4];                      // 4 d-tiles, C-layout
    #pragma unroll
    for (int i = 0; i < 4; ++i) O[i] = (f32x4){0.f, 0.f, 0.f, 0.f};
    f32x4 mrun = (f32x4){NEG_BIG, NEG_BIG, NEG_BIG, NEG_BIG};
    f32x4 lrun = (f32x4){0.f, 0.f, 0.f, 0.f};

    u16* Pw = &Pbuf[wv][0];
    const u16* vbh = VhT + (size_t)bh * HS * S_PAD;
    const u16* vbl = VlT + (size_t)bh * HS * S_PAD;

    for (int c = 0; c < 8; ++c) {
        int s0 = c * 128;
        // ---- cooperative K-chunk staging (swizzled) ----
        __syncthreads();
        {
            int row = tid >> 1, gb = (tid & 1) * 4, rx = row & 7;
            const u16* gkh = Khg + ((size_t)bh * S_PAD + s0 + row) * HS;
            const u16* gkl = Klg + ((size_t)bh * S_PAD + s0 + row) * HS;
            u16* dsth = Ksh + row * 64;
            u16* dstl = Ksl + row * 64;
            #pragma unroll
            for (int uu = 0; uu < 4; ++uu) {
                int g = gb + uu;
                int ph = (g ^ rx) << 3;
                *(u16x8*)(dsth + ph) = *(const u16x8*)(gkh + g * 8);
                *(u16x8*)(dstl + ph) = *(const u16x8*)(gkl + g * 8);
            }
        }
        __syncthreads();

        // ---- QK^T: 8 s-tiles, masked, skip fully-invalid tiles ----
        unsigned flags = 0;
        f32x4 lt[8];
        #pragma unroll
        for (int st = 0; st < 8; ++st) {
            int s = s0 + st * 16 + lm;
            bool sval = (s < S_SETS);
            int r = 0;
            if (sval) {
                int e = S_SETS - s;
                int l = __clz(e) - 22;          // level: L = 4<<l
                int i0 = s - (1024 - (1024 >> l));
                r = (i0 + 1) * (4 << l) - 1;
            }
            unsigned long long bal = __ballot(sval && (r <= twmax));
            if (bal) {
                flags |= 1u << st;
                int sl = st * 16 + lm, sx = sl & 7;
                int ph0 = sl * 64 + ((quad ^ sx) << 3);
                int ph1 = sl * 64 + (((4 + quad) ^ sx) << 3);
                bf16x8 bh0 = *(const bf16x8*)(Ksh + ph0);
                bf16x8 bh1 = *(const bf16x8*)(Ksh + ph1);
                bf16x8 bl0 = *(const bf16x8*)(Ksl + ph0);
                bf16x8 bl1 = *(const bf16x8*)(Ksl + ph1);
                f32x4 a = (f32x4){0.f, 0.f, 0.f, 0.f};
                a = mfma16(ah0, bh0, a);
                a = mfma16(ah0, bl0, a);
                a = mfma16(al0, bh0, a);
                a = mfma16(ah1, bh1, a);
                a = mfma16(ah1, bl1, a);
                a = mfma16(al1, bh1, a);
                #pragma unroll
                for (int reg = 0; reg < 4; ++reg) {
                    int t = t0w + quad * 4 + reg;
                    lt[st][reg] = (sval && t >= r) ? a[reg] * SCALE : NEG_BIG;
                }
            } else {
                lt[st] = (f32x4){NEG_BIG, NEG_BIG, NEG_BIG, NEG_BIG};
            }
        }
        if (!flags) continue;

        // ---- online softmax update (per row = quad*4+reg) ----
        f32x4 mc = lt[0];
        #pragma unroll
        for (int st = 1; st < 8; ++st)
            #pragma unroll
            for (int reg = 0; reg < 4; ++reg) mc[reg] = fmaxf(mc[reg], lt[st][reg]);
        #pragma unroll
        for (int off = 1; off < 16; off <<= 1)
            #pragma unroll
            for (int reg = 0; reg < 4; ++reg)
                mc[reg] = fmaxf(mc[reg], __shfl_xor(mc[reg], off));
        f32x4 mnew, alpha, rs = (f32x4){0.f, 0.f, 0.f, 0.f};
        #pragma unroll
        for (int reg = 0; reg < 4; ++reg) {
            mnew[reg] = fmaxf(mrun[reg], mc[reg]);
            alpha[reg] = __expf(mrun[reg] - mnew[reg]);   // 0 if mrun=NEG_BIG
        }
        #pragma unroll
        for (int st = 0; st < 8; ++st)
            #pragma unroll
            for (int reg = 0; reg < 4; ++reg) {
                float lv = lt[st][reg];
                float p = (lv > -5e29f) ? __expf(lv - mnew[reg]) : 0.f;
                rs[reg] += p;
                Pw[(quad * 4 + reg) * 136 + st * 16 + lm] = f2bf(p);
            }
        #pragma unroll
        for (int off = 1; off < 16; off <<= 1)
            #pragma unroll
            for (int reg = 0; reg < 4; ++reg) rs[reg] += __shfl_xor(rs[reg], off);
        #pragma unroll
        for (int reg = 0; reg < 4; ++reg) {
            lrun[reg] = lrun[reg] * alpha[reg] + rs[reg];
            mrun[reg] = mnew[reg];
        }
        #pragma unroll
        for (int dt = 0; dt < 4; ++dt)
            #pragma unroll
            for (int reg = 0; reg < 4; ++reg) O[dt][reg] *= alpha[reg];

        // ---- P @ V chunk (skip fully-masked 32-set segments) ----
        #pragma unroll
        for (int kc = 0; kc < 4; ++kc) {
            if (!((flags >> (2 * kc)) & 3u)) continue;
            bf16x8 afr = *(const bf16x8*)(Pw + lm * 136 + kc * 32 + quad * 8);
            #pragma unroll
            for (int dt = 0; dt < 4; ++dt) {
                size_t vo = (size_t)(dt * 16 + lm) * S_PAD + s0 + kc * 32 + quad * 8;
                bf16x8 bvh = *(const bf16x8*)(vbh + vo);
                bf16x8 bvl = *(const bf16x8*)(vbl + vo);
                O[dt] = mfma16(afr, bvh, O[dt]);
                O[dt] = mfma16(afr, bvl, O[dt]);
            }
        }
    }

    // ---- tail logit per row (lane: row=lane>>2, part=lane&3, 16 d each) ----
    {
        int rqr = lane >> 2, prt = lane & 3;
        int tt = t0w + rqr;
        int lenr = (tt & 3) + 1;
        float ktv[16];
        #pragma unroll
        for (int dd = 0; dd < 16; ++dd) ktv[dd] = 0.f;
        for (int j = 0; j < lenr; ++j) {
            const float* kp = kf + ((size_t)bh * T_SEQ + tt - j) * HS + prt * 16;
            #pragma unroll
            for (int dd = 0; dd < 16; ++dd) ktv[dd] += kp[dd];
        }
        const u16* th = qh + ((size_t)bh * T_SEQ + tt) * HS + prt * 16;
        const u16* tl_ = ql + ((size_t)bh * T_SEQ + tt) * HS + prt * 16;
        float tlp = 0.f;
        #pragma unroll
        for (int dd = 0; dd < 16; ++dd)
            tlp += (bf2f(th[dd]) + bf2f(tl_[dd])) * ktv[dd];
        tlp += __shfl_xor(tlp, 1);
        tlp += __shfl_xor(tlp, 2);
        if (prt == 0) ptl[wv][rqr] = tlp * SCALE;
    }
    __syncthreads();

    // ---- epilogue: merge tail, normalize, store bf16 ----
    int b_ = bh >> 4, h_ = bh & 15;
    #pragma unroll
    for (int reg = 0; reg < 4; ++reg) {
        int row = quad * 4 + reg;
        int t = t0w + row;
        float tl = ptl[wv][row];
        float mfin = fmaxf(mrun[reg], tl);
        float pt = __expf(tl - mfin);
        float af = __expf(mrun[reg] - mfin);
        float inv = 1.0f / (lrun[reg] * af + pt);
        int len = (t & 3) + 1;
        #pragma unroll
        for (int dt = 0; dt < 4; ++dt) {
            int d = dt * 16 + lm;
            const float* vp = vf + ((size_t)bh * T_SEQ + t) * HS + d;
            float vt = 0.f;
            for (int j = 0; j < len; ++j) vt += vp[-(j * HS)];
            float val = (O[dt][reg] * af + pt * vt) * inv;
            attout[((size_t)(b_ * T_SEQ + t)) * C_DIM + h_ * HS + d] = f2bf(val);
        }
    }
}

// -------- Kernel 4: proj GEMM, 128x128 tile (unchanged R8) ------------------
__global__ __launch_bounds__(256) void gemm_proj_t(const u16* __restrict__ a_,
                                                   const u16* __restrict__ w,
                                                   float* __restrict__ out) {
    __shared__ u16 As[128 * 32];
    __shared__ u16 Bs[128 * 32];
    int tid = threadIdx.x, wv = tid >> 6, lane = tid & 63;
    int lm = lane & 15, quad = lane >> 4;
    int mt = blockIdx.x >> 3, nt = blockIdx.x & 7;
    int wm = wv >> 1, wn = wv & 1;
    int m_off = wm * 64, n_off = wn * 64;

    const u16* gsrc;
    u16* ldst;
    int half = wv & 1;
    if (wv < 2) { gsrc = a_ + (size_t)(mt * 128 + half * 64) * C_DIM; ldst = As + half * 64 * 32; }
    else        { gsrc = w  + (size_t)(nt * 128 + half * 64) * C_DIM; ldst = Bs + half * 64 * 32; }
    int srow = lane >> 2, scol = (lane & 3) * 8;

    f32x4 acc[4][4];
    #pragma unroll
    for (int i = 0; i < 4; ++i)
        #pragma unroll
        for (int j = 0; j < 4; ++j) acc[i][j] = (f32x4){0.f, 0.f, 0.f, 0.f};

    for (int k0 = 0; k0 < C_DIM; k0 += 32) {
        __syncthreads();
        #pragma unroll
        for (int i = 0; i < 4; ++i) {
            int row = i * 16 + srow;
            __builtin_amdgcn_global_load_lds(
                GLB(gsrc + (size_t)row * C_DIM + k0 + scol),
                LDS(ldst + i * 512), 16, 0, 0);
        }
        __syncthreads();
        bf16x8 af[4], bf[4];
        #pragma unroll
        for (int i = 0; i < 4; ++i) {
            af[i] = *(const bf16x8*)(As + (m_off + i * 16 + lm) * 32 + quad * 8);
            bf[i] = *(const bf16x8*)(Bs + (n_off + i * 16 + lm) * 32 + quad * 8);
        }
        #pragma unroll
        for (int mi = 0; mi < 4; ++mi)
            #pragma unroll
            for (int ni = 0; ni < 4; ++ni)
                acc[mi][ni] = mfma16(af[mi], bf[ni], acc[mi][ni]);
    }

    #pragma unroll
    for (int mi = 0; mi < 4; ++mi)
        #pragma unroll
        for (int ni = 0; ni < 4; ++ni) {
            int n = nt * 128 + n_off + ni * 16 + lm;
            #pragma unroll
            for (int reg = 0; reg < 4; ++reg) {
                int m = mt * 128 + m_off + mi * 16 + quad * 4 + reg;
                out[(size_t)m * C_DIM + n] = acc[mi][ni][reg];
            }
        }
}

extern "C" void kernel_launch(void* const* d_in, const int* in_sizes, int n_in,
                              void* d_out, int out_size, void* d_ws, size_t ws_size,
                              hipStream_t stream) {
    const float* x     = (const float*)d_in[0];
    const float* Wattn = (const float*)d_in[1];
    const float* Wproj = (const float*)d_in[2];
    float* out = (float*)d_out;
    char* ws = (char*)d_ws;
    // workspace layout (78 MB, dead-buffer overlays)
    u16*   xh  = (u16*)(ws + 0);            //  8,388,608
    u16*   xl  = (u16*)(ws + 8388608);      //  8,388,608
    u16*   wh  = (u16*)(ws + 16777216);     //  6,291,456
    u16*   wl  = (u16*)(ws + 23068672);     //  6,291,456
    u16*   wp  = (u16*)(ws + 29360128);     //  2,097,152
    u16*   qh  = (u16*)(ws + 31457280);     //  8,388,608
    u16*   ql  = (u16*)(ws + 39845888);     //  8,388,608
    float* kf  = (float*)(ws + 48234496);   // 16,777,216
    float* vf  = (float*)(ws + 65011712);   // 16,777,216  (end 81,788,928)
    // overlays (xh/xl/wh/wl dead after gemm_qkv3_t)
    u16* Kh     = (u16*)(ws + 0);           //  4,194,304
    u16* Kl     = (u16*)(ws + 4194304);     //  4,194,304
    u16* VhT    = (u16*)(ws + 8388608);     //  4,194,304
    u16* VlT    = (u16*)(ws + 12582912);    //  4,194,304
    u16* attout = (u16*)(ws + 16777216);    //  8,388,608 (over wh/wl, ends < wp)

    hipLaunchKernelGGL(conv_split, dim3(4096), dim3(256), 0, stream, x, xh, xl, 1048576);
    hipLaunchKernelGGL(conv_split, dim3(3072), dim3(256), 0, stream, Wattn, wh, wl, 786432);
    hipLaunchKernelGGL(conv_plain, dim3(1024), dim3(256), 0, stream, Wproj, wp, 262144);
    hipLaunchKernelGGL(gemm_qkv3_t, dim3(768), dim3(256), 0, stream, xh, xl, wh, wl, qh, ql, kf, vf);
    hipLaunchKernelGGL(set_sums, dim3(32, 8), dim3(256), 0, stream, kf, vf, Kh, Kl, VhT, VlT);
    hipLaunchKernelGGL(attn_flash, dim3(32, 32), dim3(256), 0, stream,
                       qh, ql, kf, vf, Kh, Kl, VhT, VlT, attout);
    hipLaunchKernelGGL(gemm_proj_t, dim3(256), dim3(256), 0, stream, attout, wp, out);
}

// Round 10
// 280.063 us; speedup vs baseline: 8.3857x; 1.3265x over previous
//
#include <hip/hip_runtime.h>

typedef _Float16 f16x8 __attribute__((ext_vector_type(8)));
typedef unsigned short u16x8 __attribute__((ext_vector_type(8)));
typedef float f32x4  __attribute__((ext_vector_type(4)));
typedef unsigned short u16;

#define T_SEQ 2048
#define C_DIM 1024
#define NH 16
#define HS 64
#define S_SETS 1023
#define S_PAD 1024
#define SCALE 0.125f     // 1/sqrt(64)
#define NEG_BIG -1e30f

#define GLB(p) ((const __attribute__((address_space(1))) void*)(p))
#define LDS(p) ((__attribute__((address_space(3))) void*)(p))

__device__ __forceinline__ u16 f2h(float f) {
    _Float16 h = (_Float16)f;
    return __builtin_bit_cast(unsigned short, h);
}
__device__ __forceinline__ float h2f(u16 u) {
    _Float16 h = __builtin_bit_cast(_Float16, u);
    return (float)h;
}
__device__ __forceinline__ u16 f2bf(float f) {
    unsigned int x = __builtin_bit_cast(unsigned int, f);
    unsigned int r = (x + 0x7FFFu + ((x >> 16) & 1u)) >> 16;
    return (u16)r;
}
__device__ __forceinline__ f32x4 mfmah(f16x8 a, f16x8 b, f32x4 c) {
    return __builtin_amdgcn_mfma_f32_16x16x32_f16(a, b, c, 0, 0, 0);
}

// -------- Kernel 0: fp32 -> fp16 ---------------------------------------------
__global__ __launch_bounds__(256) void conv_f16(const float* __restrict__ in,
                                                u16* __restrict__ out, int n4) {
    int i = blockIdx.x * 256 + threadIdx.x;
    if (i >= n4) return;
    float4 f = ((const float4*)in)[i];
    ushort4 o;
    o.x = f2h(f.x); o.y = f2h(f.y); o.z = f2h(f.z); o.w = f2h(f.w);
    ((ushort4*)out)[i] = o;
}

// -------- Kernel 1: qkv = x @ W_attn^T, fp16 MFMA, 128x128 tile --------------
// M=4096, N=3072, K=1024. q -> fp16; k,v -> fp32 (set sums + tails).
__global__ __launch_bounds__(256) void gemm_qkv16(const u16* __restrict__ x16,
                                                  const u16* __restrict__ wa16,
                                                  u16* __restrict__ q16,
                                                  float* __restrict__ kf,
                                                  float* __restrict__ vf) {
    __shared__ u16 As[128 * 32];
    __shared__ u16 Bs[128 * 32];
    int tid = threadIdx.x, wv = tid >> 6, lane = tid & 63;
    int lm = lane & 15, quad = lane >> 4;
    int mt = blockIdx.x / 24, nt = blockIdx.x % 24;
    int wm = wv >> 1, wn = wv & 1;
    int m_off = wm * 64, n_off = wn * 64;

    const u16* gsrc;
    u16* ldst;
    int half = wv & 1;
    if (wv < 2) { gsrc = x16  + (size_t)(mt * 128 + half * 64) * C_DIM; ldst = As + half * 64 * 32; }
    else        { gsrc = wa16 + (size_t)(nt * 128 + half * 64) * C_DIM; ldst = Bs + half * 64 * 32; }
    int srow = lane >> 2, scol = (lane & 3) * 8;

    f32x4 acc[4][4];
    #pragma unroll
    for (int i = 0; i < 4; ++i)
        #pragma unroll
        for (int j = 0; j < 4; ++j) acc[i][j] = (f32x4){0.f, 0.f, 0.f, 0.f};

    for (int k0 = 0; k0 < C_DIM; k0 += 32) {
        __syncthreads();
        #pragma unroll
        for (int i = 0; i < 4; ++i) {
            int row = i * 16 + srow;
            __builtin_amdgcn_global_load_lds(
                GLB(gsrc + (size_t)row * C_DIM + k0 + scol),
                LDS(ldst + i * 512), 16, 0, 0);
        }
        __syncthreads();
        f16x8 af[4], bf[4];
        #pragma unroll
        for (int i = 0; i < 4; ++i) {
            af[i] = *(const f16x8*)(As + (m_off + i * 16 + lm) * 32 + quad * 8);
            bf[i] = *(const f16x8*)(Bs + (n_off + i * 16 + lm) * 32 + quad * 8);
        }
        #pragma unroll
        for (int mi = 0; mi < 4; ++mi)
            #pragma unroll
            for (int ni = 0; ni < 4; ++ni)
                acc[mi][ni] = mfmah(af[mi], bf[ni], acc[mi][ni]);
    }

    #pragma unroll
    for (int mi = 0; mi < 4; ++mi)
        #pragma unroll
        for (int ni = 0; ni < 4; ++ni) {
            int n = nt * 128 + n_off + ni * 16 + lm;
            int which = n >> 10, h = (n >> 6) & 15, d = n & 63;
            #pragma unroll
            for (int reg = 0; reg < 4; ++reg) {
                int m = mt * 128 + m_off + mi * 16 + quad * 4 + reg;
                int b_ = m >> 11, t = m & 2047;
                size_t oi = (((size_t)(b_ * NH + h)) * T_SEQ + t) * HS + d;
                float val = acc[mi][ni][reg];
                if (which == 0)      q16[oi] = f2h(val);
                else if (which == 1) kf[oi] = val;
                else                 vf[oi] = val;
            }
        }
}

// -------- Kernel 2: hierarchical set sums -> fp16 outputs --------------------
// Block per (bh, src, dc). K16 s-major [bh][s][d]; VT16 d-major [bh][d][s].
__global__ __launch_bounds__(256) void set_sums(const float* __restrict__ kf,
                                                const float* __restrict__ vf,
                                                u16* __restrict__ K16,
                                                u16* __restrict__ VT16) {
    int bh  = blockIdx.x;
    int src = blockIdx.y >> 2;
    int dc  = blockIdx.y & 3;
    int tid = threadIdx.x;
    __shared__ float lv0[512 * 16];
    __shared__ float lv1[256 * 16];
    const float* sp = src ? vf : kf;
    u16* op = src ? VT16 : K16;
    int dbase = dc * 16;
    for (int idx = tid; idx < 512 * 16; idx += 256) {
        int sg = idx >> 4, dd = idx & 15, d = dbase + dd;
        const float* p = sp + ((size_t)bh * T_SEQ + sg * 4) * HS + d;
        float s = p[0] + p[HS] + p[2 * HS] + p[3 * HS];
        lv0[sg * 16 + dd] = s;
        size_t o = src ? ((size_t)bh * HS + d) * S_PAD + sg
                       : ((size_t)bh * S_PAD + sg) * HS + d;
        op[o] = f2h(s);
    }
    __syncthreads();
    int nsets = 256, offset = 512, lvl = 1;
    while (nsets >= 1) {
        float* sbuf = (lvl & 1) ? lv0 : lv1;
        float* dbuf = (lvl & 1) ? lv1 : lv0;
        for (int idx = tid; idx < nsets * 16; idx += 256) {
            int i = idx >> 4, dd = idx & 15, d = dbase + dd;
            float s = sbuf[(2 * i) * 16 + dd] + sbuf[(2 * i + 1) * 16 + dd];
            dbuf[i * 16 + dd] = s;
            int so = offset + i;
            size_t o = src ? ((size_t)bh * HS + d) * S_PAD + so
                           : ((size_t)bh * S_PAD + so) * HS + d;
            op[o] = f2h(s);
        }
        __syncthreads();
        offset += nsets; nsets >>= 1; lvl++;
    }
}

// -------- Kernel 3: flash-style attention, fp16, 64 queries/block ------------
// 4 waves; wave owns 16 queries. 8 chunks of 128 sets; online softmax in regs.
// K chunk in LDS (XOR swizzle); P via per-wave LDS (C->A); V B-frags from L2.
__global__ __launch_bounds__(256) void attn_flash16(const u16* __restrict__ q16,
                                                    const float* __restrict__ kf,
                                                    const float* __restrict__ vf,
                                                    const u16* __restrict__ K16,
                                                    const u16* __restrict__ VT16,
                                                    u16* __restrict__ att16) {
    int bh = blockIdx.y;
    int t0 = blockIdx.x * 64;
    int tid = threadIdx.x, wv = tid >> 6, lane = tid & 63;
    int lm = lane & 15, quad = lane >> 4;
    int t0w = t0 + wv * 16;
    int twmax = t0w + 15;

    __shared__ u16 Ks[128 * 64];     // K chunk fp16, XOR-swizzled (16KB)
    __shared__ u16 Pbuf[4][16 * 136];// per-wave P fp16 (A-layout rows, 17.4KB)
    __shared__ float ptl[4][16];     // per-wave tail logits

    const u16* qg = q16 + ((size_t)bh * T_SEQ + t0w + lm) * HS;
    f16x8 a0 = *(const f16x8*)(qg + quad * 8);
    f16x8 a1 = *(const f16x8*)(qg + 32 + quad * 8);

    f32x4 O[4];
    #pragma unroll
    for (int i = 0; i < 4; ++i) O[i] = (f32x4){0.f, 0.f, 0.f, 0.f};
    f32x4 mrun = (f32x4){NEG_BIG, NEG_BIG, NEG_BIG, NEG_BIG};
    f32x4 lrun = (f32x4){0.f, 0.f, 0.f, 0.f};

    u16* Pw = &Pbuf[wv][0];
    const u16* vb = VT16 + (size_t)bh * HS * S_PAD;

    for (int c = 0; c < 8; ++c) {
        int s0 = c * 128;
        __syncthreads();
        {   // cooperative K-chunk staging (swizzled): 256 thr x 4 x 8 elems
            int row = tid >> 1, gb = (tid & 1) * 4, rx = row & 7;
            const u16* gk = K16 + ((size_t)bh * S_PAD + s0 + row) * HS;
            u16* dst = Ks + row * 64;
            #pragma unroll
            for (int uu = 0; uu < 4; ++uu) {
                int g = gb + uu;
                *(u16x8*)(dst + ((g ^ rx) << 3)) = *(const u16x8*)(gk + g * 8);
            }
        }
        __syncthreads();

        // QK^T: 8 s-tiles, masked, skip fully-invalid tiles
        unsigned flags = 0;
        f32x4 lt[8];
        #pragma unroll
        for (int st = 0; st < 8; ++st) {
            int s = s0 + st * 16 + lm;
            bool sval = (s < S_SETS);
            int r = 0;
            if (sval) {
                int e = S_SETS - s;
                int l = __clz(e) - 22;          // level: L = 4<<l
                int i0 = s - (1024 - (1024 >> l));
                r = (i0 + 1) * (4 << l) - 1;
            }
            unsigned long long bal = __ballot(sval && (r <= twmax));
            if (bal) {
                flags |= 1u << st;
                int sl = st * 16 + lm, sx = sl & 7;
                f16x8 b0 = *(const f16x8*)(Ks + sl * 64 + ((quad ^ sx) << 3));
                f16x8 b1 = *(const f16x8*)(Ks + sl * 64 + (((4 + quad) ^ sx) << 3));
                f32x4 a = (f32x4){0.f, 0.f, 0.f, 0.f};
                a = mfmah(a0, b0, a);
                a = mfmah(a1, b1, a);
                #pragma unroll
                for (int reg = 0; reg < 4; ++reg) {
                    int t = t0w + quad * 4 + reg;
                    lt[st][reg] = (sval && t >= r) ? a[reg] * SCALE : NEG_BIG;
                }
            } else {
                lt[st] = (f32x4){NEG_BIG, NEG_BIG, NEG_BIG, NEG_BIG};
            }
        }
        if (!flags) continue;

        // online softmax update
        f32x4 mc = lt[0];
        #pragma unroll
        for (int st = 1; st < 8; ++st)
            #pragma unroll
            for (int reg = 0; reg < 4; ++reg) mc[reg] = fmaxf(mc[reg], lt[st][reg]);
        #pragma unroll
        for (int off = 1; off < 16; off <<= 1)
            #pragma unroll
            for (int reg = 0; reg < 4; ++reg)
                mc[reg] = fmaxf(mc[reg], __shfl_xor(mc[reg], off));
        f32x4 mnew, alpha, rs = (f32x4){0.f, 0.f, 0.f, 0.f};
        #pragma unroll
        for (int reg = 0; reg < 4; ++reg) {
            mnew[reg] = fmaxf(mrun[reg], mc[reg]);
            alpha[reg] = __expf(mrun[reg] - mnew[reg]);
        }
        #pragma unroll
        for (int st = 0; st < 8; ++st)
            #pragma unroll
            for (int reg = 0; reg < 4; ++reg) {
                float lv = lt[st][reg];
                float p = (lv > -5e29f) ? __expf(lv - mnew[reg]) : 0.f;
                rs[reg] += p;
                Pw[(quad * 4 + reg) * 136 + st * 16 + lm] = f2h(p);
            }
        #pragma unroll
        for (int off = 1; off < 16; off <<= 1)
            #pragma unroll
            for (int reg = 0; reg < 4; ++reg) rs[reg] += __shfl_xor(rs[reg], off);
        #pragma unroll
        for (int reg = 0; reg < 4; ++reg) {
            lrun[reg] = lrun[reg] * alpha[reg] + rs[reg];
            mrun[reg] = mnew[reg];
        }
        #pragma unroll
        for (int dt = 0; dt < 4; ++dt)
            #pragma unroll
            for (int reg = 0; reg < 4; ++reg) O[dt][reg] *= alpha[reg];

        // P @ V chunk (skip fully-masked 32-set segments)
        #pragma unroll
        for (int kc = 0; kc < 4; ++kc) {
            if (!((flags >> (2 * kc)) & 3u)) continue;
            f16x8 afr = *(const f16x8*)(Pw + lm * 136 + kc * 32 + quad * 8);
            #pragma unroll
            for (int dt = 0; dt < 4; ++dt) {
                size_t vo = (size_t)(dt * 16 + lm) * S_PAD + s0 + kc * 32 + quad * 8;
                f16x8 bv = *(const f16x8*)(vb + vo);
                O[dt] = mfmah(afr, bv, O[dt]);
            }
        }
    }

    // tail logit per row (lane: row=lane>>2, part=lane&3, 16 d each)
    {
        int rqr = lane >> 2, prt = lane & 3;
        int tt = t0w + rqr;
        int lenr = (tt & 3) + 1;
        float ktv[16];
        #pragma unroll
        for (int dd = 0; dd < 16; ++dd) ktv[dd] = 0.f;
        for (int j = 0; j < lenr; ++j) {
            const float* kp = kf + ((size_t)bh * T_SEQ + tt - j) * HS + prt * 16;
            #pragma unroll
            for (int dd = 0; dd < 16; ++dd) ktv[dd] += kp[dd];
        }
        const u16* tq = q16 + ((size_t)bh * T_SEQ + tt) * HS + prt * 16;
        float tlp = 0.f;
        #pragma unroll
        for (int dd = 0; dd < 16; ++dd) tlp += h2f(tq[dd]) * ktv[dd];
        tlp += __shfl_xor(tlp, 1);
        tlp += __shfl_xor(tlp, 2);
        if (prt == 0) ptl[wv][rqr] = tlp * SCALE;
    }
    __syncthreads();

    // epilogue: merge tail, normalize, store fp16
    int b_ = bh >> 4, h_ = bh & 15;
    #pragma unroll
    for (int reg = 0; reg < 4; ++reg) {
        int row = quad * 4 + reg;
        int t = t0w + row;
        float tl = ptl[wv][row];
        float mfin = fmaxf(mrun[reg], tl);
        float pt = __expf(tl - mfin);
        float af = __expf(mrun[reg] - mfin);
        float inv = 1.0f / (lrun[reg] * af + pt);
        int len = (t & 3) + 1;
        #pragma unroll
        for (int dt = 0; dt < 4; ++dt) {
            int d = dt * 16 + lm;
            const float* vp = vf + ((size_t)bh * T_SEQ + t) * HS + d;
            float vt = 0.f;
            for (int j = 0; j < len; ++j) vt += vp[-(j * HS)];
            float val = (O[dt][reg] * af + pt * vt) * inv;
            att16[((size_t)(b_ * T_SEQ + t)) * C_DIM + h_ * HS + d] = f2h(val);
        }
    }
}

// -------- Kernel 4: out = attout @ W_proj^T, fp16 MFMA, fp32 out -------------
__global__ __launch_bounds__(256) void gemm_proj16(const u16* __restrict__ a_,
                                                   const u16* __restrict__ w,
                                                   float* __restrict__ out) {
    __shared__ u16 As[128 * 32];
    __shared__ u16 Bs[128 * 32];
    int tid = threadIdx.x, wv = tid >> 6, lane = tid & 63;
    int lm = lane & 15, quad = lane >> 4;
    int mt = blockIdx.x >> 3, nt = blockIdx.x & 7;
    int wm = wv >> 1, wn = wv & 1;
    int m_off = wm * 64, n_off = wn * 64;

    const u16* gsrc;
    u16* ldst;
    int half = wv & 1;
    if (wv < 2) { gsrc = a_ + (size_t)(mt * 128 + half * 64) * C_DIM; ldst = As + half * 64 * 32; }
    else        { gsrc = w  + (size_t)(nt * 128 + half * 64) * C_DIM; ldst = Bs + half * 64 * 32; }
    int srow = lane >> 2, scol = (lane & 3) * 8;

    f32x4 acc[4][4];
    #pragma unroll
    for (int i = 0; i < 4; ++i)
        #pragma unroll
        for (int j = 0; j < 4; ++j) acc[i][j] = (f32x4){0.f, 0.f, 0.f, 0.f};

    for (int k0 = 0; k0 < C_DIM; k0 += 32) {
        __syncthreads();
        #pragma unroll
        for (int i = 0; i < 4; ++i) {
            int row = i * 16 + srow;
            __builtin_amdgcn_global_load_lds(
                GLB(gsrc + (size_t)row * C_DIM + k0 + scol),
                LDS(ldst + i * 512), 16, 0, 0);
        }
        __syncthreads();
        f16x8 af[4], bf[4];
        #pragma unroll
        for (int i = 0; i < 4; ++i) {
            af[i] = *(const f16x8*)(As + (m_off + i * 16 + lm) * 32 + quad * 8);
            bf[i] = *(const f16x8*)(Bs + (n_off + i * 16 + lm) * 32 + quad * 8);
        }
        #pragma unroll
        for (int mi = 0; mi < 4; ++mi)
            #pragma unroll
            for (int ni = 0; ni < 4; ++ni)
                acc[mi][ni] = mfmah(af[mi], bf[ni], acc[mi][ni]);
    }

    #pragma unroll
    for (int mi = 0; mi < 4; ++mi)
        #pragma unroll
        for (int ni = 0; ni < 4; ++ni) {
            int n = nt * 128 + n_off + ni * 16 + lm;
            #pragma unroll
            for (int reg = 0; reg < 4; ++reg) {
                int m = mt * 128 + m_off + mi * 16 + quad * 4 + reg;
                out[(size_t)m * C_DIM + n] = acc[mi][ni][reg];
            }
        }
}

extern "C" void kernel_launch(void* const* d_in, const int* in_sizes, int n_in,
                              void* d_out, int out_size, void* d_ws, size_t ws_size,
                              hipStream_t stream) {
    const float* x     = (const float*)d_in[0];
    const float* Wattn = (const float*)d_in[1];
    const float* Wproj = (const float*)d_in[2];
    float* out = (float*)d_out;
    char* ws = (char*)d_ws;
    // workspace layout (72 MB)
    u16*   x16  = (u16*)(ws + 0);           //  8,388,608
    u16*   wa16 = (u16*)(ws + 8388608);     //  6,291,456
    u16*   wp16 = (u16*)(ws + 14680064);    //  2,097,152
    u16*   q16  = (u16*)(ws + 16777216);    //  8,388,608
    float* kf   = (float*)(ws + 25165824);  // 16,777,216
    float* vf   = (float*)(ws + 41943040);  // 16,777,216
    u16*   K16  = (u16*)(ws + 58720256);    //  4,194,304
    u16*   VT16 = (u16*)(ws + 62914560);    //  4,194,304
    u16*   att16= (u16*)(ws + 67108864);    //  8,388,608  (end 75,497,472)

    hipLaunchKernelGGL(conv_f16, dim3(4096), dim3(256), 0, stream, x, x16, 1048576);
    hipLaunchKernelGGL(conv_f16, dim3(3072), dim3(256), 0, stream, Wattn, wa16, 786432);
    hipLaunchKernelGGL(conv_f16, dim3(1024), dim3(256), 0, stream, Wproj, wp16, 262144);
    hipLaunchKernelGGL(gemm_qkv16, dim3(768), dim3(256), 0, stream, x16, wa16, q16, kf, vf);
    hipLaunchKernelGGL(set_sums, dim3(32, 8), dim3(256), 0, stream, kf, vf, K16, VT16);
    hipLaunchKernelGGL(attn_flash16, dim3(32, 32), dim3(256), 0, stream,
                       q16, kf, vf, K16, VT16, att16);
    hipLaunchKernelGGL(gemm_proj16, dim3(256), dim3(256), 0, stream, att16, wp16, out);
}

// Round 11
// 236.350 us; speedup vs baseline: 9.9367x; 1.1850x over previous
//
#include <hip/hip_runtime.h>

typedef _Float16 f16x8 __attribute__((ext_vector_type(8)));
typedef unsigned short u16x8 __attribute__((ext_vector_type(8)));
typedef float f32x4  __attribute__((ext_vector_type(4)));
typedef unsigned short u16;

#define T_SEQ 2048
#define C_DIM 1024
#define NH 16
#define HS 64
#define S_SETS 1023
#define S_PAD 1024
#define SCALE 0.125f     // 1/sqrt(64), pre-folded into q16
#define NEG_BIG -1e30f

#define GLB(p) ((const __attribute__((address_space(1))) void*)(p))
#define LDS(p) ((__attribute__((address_space(3))) void*)(p))

__device__ __forceinline__ u16 f2h(float f) {
    _Float16 h = (_Float16)f;
    return __builtin_bit_cast(unsigned short, h);
}
__device__ __forceinline__ float h2f(u16 u) {
    _Float16 h = __builtin_bit_cast(_Float16, u);
    return (float)h;
}
__device__ __forceinline__ f32x4 mfmah(f16x8 a, f16x8 b, f32x4 c) {
    return __builtin_amdgcn_mfma_f32_16x16x32_f16(a, b, c, 0, 0, 0);
}

// -------- Kernel 0: fp32 -> fp16 ---------------------------------------------
__global__ __launch_bounds__(256) void conv_f16(const float* __restrict__ in,
                                                u16* __restrict__ out, int n4) {
    int i = blockIdx.x * 256 + threadIdx.x;
    if (i >= n4) return;
    float4 f = ((const float4*)in)[i];
    ushort4 o;
    o.x = f2h(f.x); o.y = f2h(f.y); o.z = f2h(f.z); o.w = f2h(f.w);
    ((ushort4*)out)[i] = o;
}

// -------- Kernel 1: qkv = x @ W_attn^T, fp16 MFMA, 128x128 tile --------------
// q -> fp16 PRE-SCALED by 0.125; k,v -> fp16.
__global__ __launch_bounds__(256) void gemm_qkv16(const u16* __restrict__ x16,
                                                  const u16* __restrict__ wa16,
                                                  u16* __restrict__ q16,
                                                  u16* __restrict__ k16,
                                                  u16* __restrict__ v16) {
    __shared__ u16 As[128 * 32];
    __shared__ u16 Bs[128 * 32];
    int tid = threadIdx.x, wv = tid >> 6, lane = tid & 63;
    int lm = lane & 15, quad = lane >> 4;
    int mt = blockIdx.x / 24, nt = blockIdx.x % 24;
    int wm = wv >> 1, wn = wv & 1;
    int m_off = wm * 64, n_off = wn * 64;

    const u16* gsrc;
    u16* ldst;
    int half = wv & 1;
    if (wv < 2) { gsrc = x16  + (size_t)(mt * 128 + half * 64) * C_DIM; ldst = As + half * 64 * 32; }
    else        { gsrc = wa16 + (size_t)(nt * 128 + half * 64) * C_DIM; ldst = Bs + half * 64 * 32; }
    int srow = lane >> 2, scol = (lane & 3) * 8;

    f32x4 acc[4][4];
    #pragma unroll
    for (int i = 0; i < 4; ++i)
        #pragma unroll
        for (int j = 0; j < 4; ++j) acc[i][j] = (f32x4){0.f, 0.f, 0.f, 0.f};

    for (int k0 = 0; k0 < C_DIM; k0 += 32) {
        __syncthreads();
        #pragma unroll
        for (int i = 0; i < 4; ++i) {
            int row = i * 16 + srow;
            __builtin_amdgcn_global_load_lds(
                GLB(gsrc + (size_t)row * C_DIM + k0 + scol),
                LDS(ldst + i * 512), 16, 0, 0);
        }
        __syncthreads();
        f16x8 af[4], bf[4];
        #pragma unroll
        for (int i = 0; i < 4; ++i) {
            af[i] = *(const f16x8*)(As + (m_off + i * 16 + lm) * 32 + quad * 8);
            bf[i] = *(const f16x8*)(Bs + (n_off + i * 16 + lm) * 32 + quad * 8);
        }
        #pragma unroll
        for (int mi = 0; mi < 4; ++mi)
            #pragma unroll
            for (int ni = 0; ni < 4; ++ni)
                acc[mi][ni] = mfmah(af[mi], bf[ni], acc[mi][ni]);
    }

    #pragma unroll
    for (int mi = 0; mi < 4; ++mi)
        #pragma unroll
        for (int ni = 0; ni < 4; ++ni) {
            int n = nt * 128 + n_off + ni * 16 + lm;
            int which = n >> 10, h = (n >> 6) & 15, d = n & 63;
            #pragma unroll
            for (int reg = 0; reg < 4; ++reg) {
                int m = mt * 128 + m_off + mi * 16 + quad * 4 + reg;
                int b_ = m >> 11, t = m & 2047;
                size_t oi = (((size_t)(b_ * NH + h)) * T_SEQ + t) * HS + d;
                float val = acc[mi][ni][reg];
                if (which == 0)      q16[oi] = f2h(val * SCALE);
                else if (which == 1) k16[oi] = f2h(val);
                else                 v16[oi] = f2h(val);
            }
        }
}

// -------- Kernel 2: hierarchical set sums (fp16 in) -> fp16 outputs ----------
__global__ __launch_bounds__(256) void set_sums(const u16* __restrict__ k16,
                                                const u16* __restrict__ v16,
                                                u16* __restrict__ K16,
                                                u16* __restrict__ VT16) {
    int bh  = blockIdx.x;
    int src = blockIdx.y >> 2;
    int dc  = blockIdx.y & 3;
    int tid = threadIdx.x;
    __shared__ float lv0[512 * 16];
    __shared__ float lv1[256 * 16];
    const u16* sp = src ? v16 : k16;
    u16* op = src ? VT16 : K16;
    int dbase = dc * 16;
    for (int idx = tid; idx < 512 * 16; idx += 256) {
        int sg = idx >> 4, dd = idx & 15, d = dbase + dd;
        const u16* p = sp + ((size_t)bh * T_SEQ + sg * 4) * HS + d;
        float s = h2f(p[0]) + h2f(p[HS]) + h2f(p[2 * HS]) + h2f(p[3 * HS]);
        lv0[sg * 16 + dd] = s;
        size_t o = src ? ((size_t)bh * HS + d) * S_PAD + sg
                       : ((size_t)bh * S_PAD + sg) * HS + d;
        op[o] = f2h(s);
    }
    __syncthreads();
    int nsets = 256, offset = 512, lvl = 1;
    while (nsets >= 1) {
        float* sbuf = (lvl & 1) ? lv0 : lv1;
        float* dbuf = (lvl & 1) ? lv1 : lv0;
        for (int idx = tid; idx < nsets * 16; idx += 256) {
            int i = idx >> 4, dd = idx & 15, d = dbase + dd;
            float s = sbuf[(2 * i) * 16 + dd] + sbuf[(2 * i + 1) * 16 + dd];
            dbuf[i * 16 + dd] = s;
            int so = offset + i;
            size_t o = src ? ((size_t)bh * HS + d) * S_PAD + so
                           : ((size_t)bh * S_PAD + so) * HS + d;
            op[o] = f2h(s);
        }
        __syncthreads();
        offset += nsets; nsets >>= 1; lvl++;
    }
}

// -------- Kernel 3: flash attention, fp16, load-balanced pairing -------------
// Waves 0-1: queries [32bx, 32bx+32); waves 2-3: [2016-32bx, 2048-32bx).
// Per-block work ~uniform. Online softmax in regs; flag-gated exp.
__global__ __launch_bounds__(256) void attn_flash16(const u16* __restrict__ q16,
                                                    const u16* __restrict__ k16,
                                                    const u16* __restrict__ v16,
                                                    const u16* __restrict__ K16,
                                                    const u16* __restrict__ VT16,
                                                    u16* __restrict__ att16) {
    int bh = blockIdx.y;
    int tid = threadIdx.x, wv = tid >> 6, lane = tid & 63;
    int lm = lane & 15, quad = lane >> 4;
    int tgrp = (wv < 2) ? (32 * blockIdx.x) : (2016 - 32 * blockIdx.x);
    int t0w = tgrp + (wv & 1) * 16;
    int twmax = t0w + 15;

    __shared__ u16 Ks[128 * 64];     // K chunk fp16, XOR-swizzled (16KB)
    __shared__ u16 Pbuf[4][16 * 136];// per-wave P fp16 (A-layout rows)
    __shared__ float ptl[4][16];     // per-wave tail logits

    const u16* qg = q16 + ((size_t)bh * T_SEQ + t0w + lm) * HS;
    f16x8 a0 = *(const f16x8*)(qg + quad * 8);
    f16x8 a1 = *(const f16x8*)(qg + 32 + quad * 8);

    f32x4 O[4];
    #pragma unroll
    for (int i = 0; i < 4; ++i) O[i] = (f32x4){0.f, 0.f, 0.f, 0.f};
    f32x4 mrun = (f32x4){NEG_BIG, NEG_BIG, NEG_BIG, NEG_BIG};
    f32x4 lrun = (f32x4){0.f, 0.f, 0.f, 0.f};

    u16* Pw = &Pbuf[wv][0];
    const u16* vb = VT16 + (size_t)bh * HS * S_PAD;

    for (int c = 0; c < 8; ++c) {
        int s0 = c * 128;
        __syncthreads();
        {   // cooperative K-chunk staging (swizzled)
            int row = tid >> 1, gb = (tid & 1) * 4, rx = row & 7;
            const u16* gk = K16 + ((size_t)bh * S_PAD + s0 + row) * HS;
            u16* dst = Ks + row * 64;
            #pragma unroll
            for (int uu = 0; uu < 4; ++uu) {
                int g = gb + uu;
                *(u16x8*)(dst + ((g ^ rx) << 3)) = *(const u16x8*)(gk + g * 8);
            }
        }
        __syncthreads();

        // QK^T: 8 s-tiles, masked, wave-uniform skip
        unsigned flags = 0;
        f32x4 lt[8];
        #pragma unroll
        for (int st = 0; st < 8; ++st) {
            int s = s0 + st * 16 + lm;
            bool sval = (s < S_SETS);
            int r = 0;
            if (sval) {
                int e = S_SETS - s;
                int l = __clz(e) - 22;          // level: L = 4<<l
                int i0 = s - (1024 - (1024 >> l));
                r = (i0 + 1) * (4 << l) - 1;
            }
            unsigned long long bal = __ballot(sval && (r <= twmax));
            if (bal) {
                flags |= 1u << st;
                int sl = st * 16 + lm, sx = sl & 7;
                f16x8 b0 = *(const f16x8*)(Ks + sl * 64 + ((quad ^ sx) << 3));
                f16x8 b1 = *(const f16x8*)(Ks + sl * 64 + (((4 + quad) ^ sx) << 3));
                f32x4 a = (f32x4){0.f, 0.f, 0.f, 0.f};
                a = mfmah(a0, b0, a);
                a = mfmah(a1, b1, a);
                #pragma unroll
                for (int reg = 0; reg < 4; ++reg) {
                    int t = t0w + quad * 4 + reg;
                    lt[st][reg] = (sval && t >= r) ? a[reg] : NEG_BIG;
                }
            }
        }
        if (!flags) continue;

        // online softmax update (flag-gated exp)
        f32x4 mc = (f32x4){NEG_BIG, NEG_BIG, NEG_BIG, NEG_BIG};
        #pragma unroll
        for (int st = 0; st < 8; ++st)
            if ((flags >> st) & 1u)
                #pragma unroll
                for (int reg = 0; reg < 4; ++reg) mc[reg] = fmaxf(mc[reg], lt[st][reg]);
        #pragma unroll
        for (int off = 1; off < 16; off <<= 1)
            #pragma unroll
            for (int reg = 0; reg < 4; ++reg)
                mc[reg] = fmaxf(mc[reg], __shfl_xor(mc[reg], off));
        f32x4 mnew, alpha, rs = (f32x4){0.f, 0.f, 0.f, 0.f};
        #pragma unroll
        for (int reg = 0; reg < 4; ++reg) {
            mnew[reg] = fmaxf(mrun[reg], mc[reg]);
            alpha[reg] = __expf(mrun[reg] - mnew[reg]);
        }
        #pragma unroll
        for (int st = 0; st < 8; ++st) {
            if ((flags >> st) & 1u) {
                #pragma unroll
                for (int reg = 0; reg < 4; ++reg) {
                    float lv = lt[st][reg];
                    float p = (lv > -5e29f) ? __expf(lv - mnew[reg]) : 0.f;
                    rs[reg] += p;
                    Pw[(quad * 4 + reg) * 136 + st * 16 + lm] = f2h(p);
                }
            } else {
                #pragma unroll
                for (int reg = 0; reg < 4; ++reg)
                    Pw[(quad * 4 + reg) * 136 + st * 16 + lm] = 0;
            }
        }
        #pragma unroll
        for (int off = 1; off < 16; off <<= 1)
            #pragma unroll
            for (int reg = 0; reg < 4; ++reg) rs[reg] += __shfl_xor(rs[reg], off);
        #pragma unroll
        for (int reg = 0; reg < 4; ++reg) {
            lrun[reg] = lrun[reg] * alpha[reg] + rs[reg];
            mrun[reg] = mnew[reg];
        }
        #pragma unroll
        for (int dt = 0; dt < 4; ++dt)
            #pragma unroll
            for (int reg = 0; reg < 4; ++reg) O[dt][reg] *= alpha[reg];

        // P @ V chunk (skip fully-masked 32-set segments)
        #pragma unroll
        for (int kc = 0; kc < 4; ++kc) {
            if (!((flags >> (2 * kc)) & 3u)) continue;
            f16x8 afr = *(const f16x8*)(Pw + lm * 136 + kc * 32 + quad * 8);
            #pragma unroll
            for (int dt = 0; dt < 4; ++dt) {
                size_t vo = (size_t)(dt * 16 + lm) * S_PAD + s0 + kc * 32 + quad * 8;
                f16x8 bv = *(const f16x8*)(vb + vo);
                O[dt] = mfmah(afr, bv, O[dt]);
            }
        }
    }

    // tail logit per row (q16 pre-scaled -> no SCALE here)
    {
        int rqr = lane >> 2, prt = lane & 3;
        int tt = t0w + rqr;
        int lenr = (tt & 3) + 1;
        float ktv[16];
        #pragma unroll
        for (int dd = 0; dd < 16; ++dd) ktv[dd] = 0.f;
        for (int j = 0; j < lenr; ++j) {
            const u16* kp = k16 + ((size_t)bh * T_SEQ + tt - j) * HS + prt * 16;
            #pragma unroll
            for (int dd = 0; dd < 16; ++dd) ktv[dd] += h2f(kp[dd]);
        }
        const u16* tq = q16 + ((size_t)bh * T_SEQ + tt) * HS + prt * 16;
        float tlp = 0.f;
        #pragma unroll
        for (int dd = 0; dd < 16; ++dd) tlp += h2f(tq[dd]) * ktv[dd];
        tlp += __shfl_xor(tlp, 1);
        tlp += __shfl_xor(tlp, 2);
        if (prt == 0) ptl[wv][rqr] = tlp;
    }
    __syncthreads();

    // epilogue: merge tail, normalize, store fp16
    int b_ = bh >> 4, h_ = bh & 15;
    #pragma unroll
    for (int reg = 0; reg < 4; ++reg) {
        int row = quad * 4 + reg;
        int t = t0w + row;
        float tl = ptl[wv][row];
        float mfin = fmaxf(mrun[reg], tl);
        float pt = __expf(tl - mfin);
        float af = __expf(mrun[reg] - mfin);
        float inv = 1.0f / (lrun[reg] * af + pt);
        int len = (t & 3) + 1;
        #pragma unroll
        for (int dt = 0; dt < 4; ++dt) {
            int d = dt * 16 + lm;
            const u16* vp = v16 + ((size_t)bh * T_SEQ + t) * HS + d;
            float vt = 0.f;
            for (int j = 0; j < len; ++j) vt += h2f(vp[-(j * HS)]);
            float val = (O[dt][reg] * af + pt * vt) * inv;
            att16[((size_t)(b_ * T_SEQ + t)) * C_DIM + h_ * HS + d] = f2h(val);
        }
    }
}

// -------- Kernel 4: out = attout @ W_proj^T, fp16 MFMA, fp32 out -------------
__global__ __launch_bounds__(256) void gemm_proj16(const u16* __restrict__ a_,
                                                   const u16* __restrict__ w,
                                                   float* __restrict__ out) {
    __shared__ u16 As[128 * 32];
    __shared__ u16 Bs[128 * 32];
    int tid = threadIdx.x, wv = tid >> 6, lane = tid & 63;
    int lm = lane & 15, quad = lane >> 4;
    int mt = blockIdx.x >> 3, nt = blockIdx.x & 7;
    int wm = wv >> 1, wn = wv & 1;
    int m_off = wm * 64, n_off = wn * 64;

    const u16* gsrc;
    u16* ldst;
    int half = wv & 1;
    if (wv < 2) { gsrc = a_ + (size_t)(mt * 128 + half * 64) * C_DIM; ldst = As + half * 64 * 32; }
    else        { gsrc = w  + (size_t)(nt * 128 + half * 64) * C_DIM; ldst = Bs + half * 64 * 32; }
    int srow = lane >> 2, scol = (lane & 3) * 8;

    f32x4 acc[4][4];
    #pragma unroll
    for (int i = 0; i < 4; ++i)
        #pragma unroll
        for (int j = 0; j < 4; ++j) acc[i][j] = (f32x4){0.f, 0.f, 0.f, 0.f};

    for (int k0 = 0; k0 < C_DIM; k0 += 32) {
        __syncthreads();
        #pragma unroll
        for (int i = 0; i < 4; ++i) {
            int row = i * 16 + srow;
            __builtin_amdgcn_global_load_lds(
                GLB(gsrc + (size_t)row * C_DIM + k0 + scol),
                LDS(ldst + i * 512), 16, 0, 0);
        }
        __syncthreads();
        f16x8 af[4], bf[4];
        #pragma unroll
        for (int i = 0; i < 4; ++i) {
            af[i] = *(const f16x8*)(As + (m_off + i * 16 + lm) * 32 + quad * 8);
            bf[i] = *(const f16x8*)(Bs + (n_off + i * 16 + lm) * 32 + quad * 8);
        }
        #pragma unroll
        for (int mi = 0; mi < 4; ++mi)
            #pragma unroll
            for (int ni = 0; ni < 4; ++ni)
                acc[mi][ni] = mfmah(af[mi], bf[ni], acc[mi][ni]);
    }

    #pragma unroll
    for (int mi = 0; mi < 4; ++mi)
        #pragma unroll
        for (int ni = 0; ni < 4; ++ni) {
            int n = nt * 128 + n_off + ni * 16 + lm;
            #pragma unroll
            for (int reg = 0; reg < 4; ++reg) {
                int m = mt * 128 + m_off + mi * 16 + quad * 4 + reg;
                out[(size_t)m * C_DIM + n] = acc[mi][ni][reg];
            }
        }
}

extern "C" void kernel_launch(void* const* d_in, const int* in_sizes, int n_in,
                              void* d_out, int out_size, void* d_ws, size_t ws_size,
                              hipStream_t stream) {
    const float* x     = (const float*)d_in[0];
    const float* Wattn = (const float*)d_in[1];
    const float* Wproj = (const float*)d_in[2];
    float* out = (float*)d_out;
    char* ws = (char*)d_ws;
    // workspace layout (58.7 MB)
    u16* x16   = (u16*)(ws + 0);           //  8,388,608
    u16* wa16  = (u16*)(ws + 8388608);     //  6,291,456
    u16* wp16  = (u16*)(ws + 14680064);    //  2,097,152
    u16* q16   = (u16*)(ws + 16777216);    //  8,388,608 (pre-scaled by 1/8)
    u16* k16   = (u16*)(ws + 25165824);    //  8,388,608
    u16* v16   = (u16*)(ws + 33554432);    //  8,388,608
    u16* K16   = (u16*)(ws + 41943040);    //  4,194,304
    u16* VT16  = (u16*)(ws + 46137344);    //  4,194,304
    u16* att16 = (u16*)(ws + 50331648);    //  8,388,608  (end 58,720,256)

    hipLaunchKernelGGL(conv_f16, dim3(4096), dim3(256), 0, stream, x, x16, 1048576);
    hipLaunchKernelGGL(conv_f16, dim3(3072), dim3(256), 0, stream, Wattn, wa16, 786432);
    hipLaunchKernelGGL(conv_f16, dim3(1024), dim3(256), 0, stream, Wproj, wp16, 262144);
    hipLaunchKernelGGL(gemm_qkv16, dim3(768), dim3(256), 0, stream, x16, wa16, q16, k16, v16);
    hipLaunchKernelGGL(set_sums, dim3(32, 8), dim3(256), 0, stream, k16, v16, K16, VT16);
    hipLaunchKernelGGL(attn_flash16, dim3(32, 32), dim3(256), 0, stream,
                       q16, k16, v16, K16, VT16, att16);
    hipLaunchKernelGGL(gemm_proj16, dim3(256), dim3(256), 0, stream, att16, wp16, out);
}